// Round 9
// baseline (292.411 us; speedup 1.0000x reference)
//
#include <hip/hip_runtime.h>
#include <hip/hip_bf16.h>
#include <math.h>

// EpisodicMemory fused pipeline for MI355X (gfx950).
// B=16384, HID=1024, SLOTS=64, KD=32.
// Round 9: front-end fused into ONE kernel (convert x + qk MFMA + softmax +
// retrieve); k_gemm = 128x256 tile (A re-read 8x not 16x), 8 waves of 64x64,
// launch_bounds(512,4) -> 2 independent blocks/CU, single 48KB LDS buffer,
// simple 2-barrier loop, both-sides chunk swizzle (0 conflicts).

typedef float    f32x4 __attribute__((ext_vector_type(4)));
typedef short    s16x8 __attribute__((ext_vector_type(8)));
typedef unsigned short u16;
typedef unsigned short u16x8 __attribute__((ext_vector_type(8)));

#define MFMA_BF16(a,b,c) __builtin_amdgcn_mfma_f32_16x16x32_bf16((a),(b),(c),0,0,0)

__device__ __forceinline__ void async16(void* lds, const void* g) {
  __builtin_amdgcn_global_load_lds((const __attribute__((address_space(1))) void*)g,
                                   (__attribute__((address_space(3))) void*)lds, 16, 0, 0);
}

__device__ __forceinline__ u16 f2bf(float f) {
  unsigned u = __float_as_uint(f);
  u += 0x7fffu + ((u >> 16) & 1u);   // RNE
  return (u16)(u >> 16);
}
__device__ __forceinline__ float bf2f(u16 h) {
  return __uint_as_float(((unsigned)h) << 16);
}

// ---------------- K0: slot prep + key_w/mem_vals bf16 conversion ------------
__global__ __launch_bounds__(256) void k_prep(
    const float* __restrict__ mem_keys, const float* __restrict__ pos_table,
    const int* __restrict__ slot_order, const float* __restrict__ mem_age,
    const float* __restrict__ mem_conf, const float* __restrict__ key_w,
    const float* __restrict__ mem_vals,
    float* __restrict__ kwp /*[64][33]*/, float* __restrict__ biasv,
    u16* __restrict__ Wk, u16* __restrict__ Vals) {
  int tid = threadIdx.x;
  if (tid < 64) {                      // wave 0: per-slot salience + keys
    int s = tid;
    float age  = mem_age[s];
    float freq = fmaxf(age, 1.0f);
    float fm = freq;
    #pragma unroll
    for (int o = 32; o; o >>= 1) fm = fmaxf(fm, __shfl_xor(fm, o));
    float freq_norm = logf(freq + 1.0f) / (logf(fm + 2.0f) + 1e-8f);
    float recency = expf(-age * (1.0f/200.0f));
    biasv[s] = 0.2f*recency + 0.15f*freq_norm + 0.1f*mem_conf[s] + 0.08f;

    int idx = slot_order[s] & 63;
    float k[32]; float ss = 0.f;
    #pragma unroll
    for (int d = 0; d < 32; d++) {
      float v = mem_keys[s*32+d] + 0.1f*pos_table[idx*32+d];
      k[d] = v; ss += v*v;
    }
    float inv = 1.0f / fmaxf(sqrtf(ss), 1e-12f);
    #pragma unroll
    for (int d = 0; d < 32; d++) kwp[s*33+d] = k[d]*inv;
  }
  // all 256 threads: key_w (32768 f32) and mem_vals (65536 f32) -> bf16
  for (int g = tid; g < 8192; g += 256) {               // float4 groups
    float4 v = ((const float4*)key_w)[g];
    ushort4 o; o.x=f2bf(v.x); o.y=f2bf(v.y); o.z=f2bf(v.z); o.w=f2bf(v.w);
    *(ushort4*)(Wk + (size_t)g*4) = o;
  }
  for (int g = tid; g < 16384; g += 256) {
    float4 v = ((const float4*)mem_vals)[g];
    ushort4 o; o.x=f2bf(v.x); o.y=f2bf(v.y); o.z=f2bf(v.z); o.w=f2bf(v.w);
    *(ushort4*)(Vals + (size_t)g*4) = o;
  }
}

// ---------------- K1: fused front (x->bf16, qk, softmax, retrieve) ----------
// blocks 0..255: 64 x-rows each. blocks 256..383: weight conversion.
__global__ __launch_bounds__(256) void k_front(
    const float* __restrict__ x, const float* __restrict__ gate_w,
    const float* __restrict__ out_w, const u16* __restrict__ Wk,
    const u16* __restrict__ Vals, const float* __restrict__ kwp,
    const float* __restrict__ biasv, u16* __restrict__ A,
    u16* __restrict__ Wcat) {
  const int b = blockIdx.x, tid = threadIdx.x;
  if (b >= 256) {
    // gate_w/out_w -> Wcat [2048][2048], row p=g*32+h*16+c <- (h?out:gate)[g*16+c]
    const int NW = 524288;   // float4 groups per weight
    for (int g = (b-256)*256 + tid; g < 2*NW; g += 128*256) {
      float4 v; int t, pb;
      if (g < NW) { t = g;      v = ((const float4*)gate_w)[t]; pb = 0; }
      else        { t = g - NW; v = ((const float4*)out_w)[t];  pb = 16; }
      int row = t >> 9, grp = t & 511;
      int p = ((row>>4)<<5) + pb + (row&15);
      ushort4 o; o.x=f2bf(v.x); o.y=f2bf(v.y); o.z=f2bf(v.z); o.w=f2bf(v.w);
      *(ushort4*)(Wcat + ((size_t)p*2048 + grp*4)) = o;
    }
    return;
  }

  __shared__ __align__(16) u16 sX[64*72];     // x tile bf16, padded stride 72
  __shared__ float sQK[64*33];
  __shared__ float sK[64*33];
  __shared__ float sBias[64];
  __shared__ float sQn[64*32];
  __shared__ float sAttn[64*64];

  const int lane = tid & 63, w = tid >> 6;
  const int ln15 = lane & 15, hi = lane >> 4;
  const size_t r0 = (size_t)b * 64;

  for (int i = tid; i < 64*33; i += 256) sK[i] = kwp[i];
  if (tid < 64) sBias[tid] = biasv[tid];

  // ---- qk = x @ key_w^T via MFMA, fused with x->bf16 conversion ----
  f32x4 acc0 = {0.f,0.f,0.f,0.f}, acc1 = {0.f,0.f,0.f,0.f};
  const int xrow = tid >> 4, xc4 = tid & 15;
  for (int k0 = 0; k0 < 1024; k0 += 64) {
    #pragma unroll
    for (int j = 0; j < 4; j++) {
      int row = xrow + j*16;
      float4 v = *(const float4*)&x[(r0+row)*1024 + k0 + xc4*4];
      ushort4 o; o.x=f2bf(v.x); o.y=f2bf(v.y); o.z=f2bf(v.z); o.w=f2bf(v.w);
      *(ushort4*)&sX[row*72 + xc4*4] = o;
      *(ushort4*)&A[(r0+row)*2048 + k0 + xc4*4] = o;    // combined left half
    }
    __syncthreads();
    #pragma unroll
    for (int kk = 0; kk < 2; kk++) {
      int kb = kk*32 + hi*8;
      s16x8 a  = *(const s16x8*)&sX[(w*16 + ln15)*72 + kb];
      s16x8 b0 = *(const s16x8*)&Wk[(size_t)ln15*1024 + k0 + kb];
      s16x8 b1 = *(const s16x8*)&Wk[(size_t)(16+ln15)*1024 + k0 + kb];
      acc0 = MFMA_BF16(a, b0, acc0);
      acc1 = MFMA_BF16(a, b1, acc1);
    }
    __syncthreads();
  }
  #pragma unroll
  for (int i = 0; i < 4; i++) {
    sQK[(w*16 + hi*4 + i)*33 + ln15]      = acc0[i];
    sQK[(w*16 + hi*4 + i)*33 + 16 + ln15] = acc1[i];
  }
  __syncthreads();

  // ---- softmax over 64 slots (wave handles its 16 rows) ----
  int d = lane & 31;
  for (int j = 0; j < 16; j++) {
    int rl = w*16 + j;
    float v = sQK[rl*33 + d];
    float sq = v*v;
    #pragma unroll
    for (int o = 16; o; o >>= 1) sq += __shfl_xor(sq, o);   // 32-group sum
    float qn = v / fmaxf(sqrtf(sq), 1e-12f);
    if (lane < 32) sQn[rl*32 + d] = qn;
    float accs = 0.f;
    #pragma unroll
    for (int dd = 0; dd < 32; dd++) accs += sK[lane*33+dd] * sQn[rl*32+dd];
    float sim = accs * 0.17677669529663687f;   // 1/sqrt(32)
    float sal = fminf(fmaxf(0.45f*sim + sBias[lane], 0.0f), 1.0f);
    float mx = sal;
    #pragma unroll
    for (int o = 32; o; o >>= 1) mx = fmaxf(mx, __shfl_xor(mx, o));
    float e = expf(sal - mx);
    float sm = e;
    #pragma unroll
    for (int o = 32; o; o >>= 1) sm += __shfl_xor(sm, o);
    sAttn[rl*64 + lane] = e / sm;
  }
  __syncthreads();

  // ---- retrieved = attn @ mem_vals; 4 sweeps of 16 rows ----
  for (int g = 0; g < 4; g++) {
    float acc[4][16];
    #pragma unroll
    for (int j = 0; j < 4; j++)
      #pragma unroll
      for (int i = 0; i < 16; i++) acc[j][i] = 0.f;
    const u16* vp = Vals + lane*16;
    for (int s = 0; s < 64; s++) {
      s16x8 v0 = *(const s16x8*)(vp + (size_t)s*1024);
      s16x8 v1 = *(const s16x8*)(vp + (size_t)s*1024 + 8);
      float vf[16];
      #pragma unroll
      for (int i = 0; i < 8; i++) { vf[i] = bf2f((u16)v0[i]); vf[8+i] = bf2f((u16)v1[i]); }
      #pragma unroll
      for (int j = 0; j < 4; j++) {
        float a = sAttn[(g*16 + w*4 + j)*64 + s];
        #pragma unroll
        for (int i = 0; i < 16; i++) acc[j][i] += a * vf[i];
      }
    }
    #pragma unroll
    for (int j = 0; j < 4; j++) {
      size_t r = r0 + g*16 + w*4 + j;
      u16x8 o0, o1;
      #pragma unroll
      for (int i = 0; i < 8; i++) { o0[i] = f2bf(acc[j][i]); o1[i] = f2bf(acc[j][8+i]); }
      u16* dst = A + r*2048 + 1024 + lane*16;
      *(u16x8*)dst = o0;
      *(u16x8*)(dst + 8) = o1;
    }
  }
}

// ---------------- K2: single interleaved GEMM + fused epilogue --------------
// C = combined[16384,2048] @ Wcat[2048,2048]^T.
// 128x256 tile, 8 waves (2x4, wave=64x64), BK=64, single 48KB LDS buffer,
// plain 2-barrier loop; 2 independent blocks/CU (launch_bounds(512,4)).
__global__ __launch_bounds__(512, 4) void k_gemm(
    const u16* __restrict__ A, const u16* __restrict__ Wcat,
    const float* __restrict__ out_b, const float* __restrict__ gate_b,
    float* __restrict__ y) {
  __shared__ __align__(16) u16 sA[8192];    // 128 rows x 64 (swizzled)
  __shared__ __align__(16) u16 sB[16384];   // 256 rows x 64 (swizzled)

  const int tid = threadIdx.x, lane = tid & 63, w = tid >> 6;
  const int ln15 = lane & 15, hi = lane >> 4, p7 = ln15 & 7;
  const int wr = w >> 2, wc = w & 3;

  // 1024 blocks: colblk = XCD (8 panels, 1 per XCD L2), rowblk swept
  const int colblk = blockIdx.x & 7;
  const int rowblk = blockIdx.x >> 3;
  const size_t r0 = (size_t)rowblk * 128;
  const size_t c0 = (size_t)colblk * 256;

  const u16* gA = A    + r0 * 2048;
  const u16* gB = Wcat + c0 * 2048;

  // staging: A 1024 chunks (2/thread), B 2048 chunks (4/thread); physical
  // chunk pc of row r holds logical chunk pc ^ (r&7) (inv-swz global source).
  int offA[2], offB[4];
  #pragma unroll
  for (int j = 0; j < 2; j++) {
    int c = tid + j*512, row = c >> 3, pc = c & 7;
    offA[j] = row*2048 + ((pc ^ (row & 7)) << 3);
  }
  #pragma unroll
  for (int j = 0; j < 4; j++) {
    int c = tid + j*512, row = c >> 3, pc = c & 7;
    offB[j] = row*2048 + ((pc ^ (row & 7)) << 3);
  }

  const int ck0 = (hi ^ p7) * 8;          // kk=0: logical chunk hi
  const int ck1 = ((4 | hi) ^ p7) * 8;    // kk=1: logical chunk 4|hi
  const int arow = (wr*64 + ln15) * 64;   // + m*1024
  const int brow = (wc*64 + ln15) * 64;   // + n*1024

  f32x4 acc[4][4];
  #pragma unroll
  for (int m = 0; m < 4; m++)
    #pragma unroll
    for (int n = 0; n < 4; n++) acc[m][n] = {0.f, 0.f, 0.f, 0.f};

  for (int kt = 0; kt < 32; ++kt) {
    const int ko = kt * 64;
    #pragma unroll
    for (int j = 0; j < 2; j++) async16(&sA[(tid + j*512)*8], gA + offA[j] + ko);
    #pragma unroll
    for (int j = 0; j < 4; j++) async16(&sB[(tid + j*512)*8], gB + offB[j] + ko);
    __syncthreads();
    #pragma unroll
    for (int kk = 0; kk < 2; kk++) {
      const int ck = kk ? ck1 : ck0;
      s16x8 af[4], bfr[4];
      #pragma unroll
      for (int m = 0; m < 4; m++) af[m]  = *(const s16x8*)&sA[arow + m*1024 + ck];
      #pragma unroll
      for (int n = 0; n < 4; n++) bfr[n] = *(const s16x8*)&sB[brow + n*1024 + ck];
      #pragma unroll
      for (int m = 0; m < 4; m++)
        #pragma unroll
        for (int n = 0; n < 4; n++)
          acc[m][n] = MFMA_BF16(af[m], bfr[n], acc[m][n]);
    }
    __syncthreads();
  }

  // epilogue: Wcat row p = c0 + wc*64 + n*16 + ln15; n even=gate, odd=out,
  // ocol = colblk*128 + wc*32 + (n>>1)*16 + ln15. y pre-LN (f32, in d_out).
  #pragma unroll
  for (int s = 0; s < 2; s++) {
    int ocol = colblk*128 + wc*32 + s*16 + ln15;
    float gbv = gate_b[ocol], obv = out_b[ocol];
    #pragma unroll
    for (int m = 0; m < 4; m++) {
      #pragma unroll
      for (int i = 0; i < 4; i++) {
        size_t r = r0 + wr*64 + m*16 + hi*4 + i;
        float gg = acc[m][s*2+0][i] + gbv;
        float go = acc[m][s*2+1][i] + obv;
        float h  = 0.5f*go*(1.0f + erff(go*0.70710678118654752f));  // exact gelu
        float sg = 1.0f/(1.0f + __expf(-gg));
        float rv = bf2f(A[r*2048 + 1024 + ocol]);
        float xv = bf2f(A[r*2048 + ocol]);
        y[r*1024 + ocol] = h + sg*rv + (1.0f - sg)*xv;
      }
    }
  }
}

// ---------------- K3: LayerNorm in place (wave per row) ---------------------
__global__ __launch_bounds__(256) void k_ln(float* __restrict__ y, const float* __restrict__ g,
                                            const float* __restrict__ b) {
  int row  = blockIdx.x*4 + (threadIdx.x >> 6);
  int lane = threadIdx.x & 63;
  float4* p = (float4*)(y + (size_t)row*1024);
  float4 v[4];
  #pragma unroll
  for (int i = 0; i < 4; i++) v[i] = p[lane + 64*i];
  float s = 0.f;
  #pragma unroll
  for (int i = 0; i < 4; i++) s += v[i].x + v[i].y + v[i].z + v[i].w;
  #pragma unroll
  for (int o = 32; o; o >>= 1) s += __shfl_xor(s, o);
  float mu = s * (1.0f/1024.0f);
  float vs = 0.f;
  #pragma unroll
  for (int i = 0; i < 4; i++) {
    float d0 = v[i].x-mu, d1 = v[i].y-mu, d2 = v[i].z-mu, d3 = v[i].w-mu;
    vs += d0*d0 + d1*d1 + d2*d2 + d3*d3;
  }
  #pragma unroll
  for (int o = 32; o; o >>= 1) vs += __shfl_xor(vs, o);
  float inv = 1.0f / sqrtf(vs*(1.0f/1024.0f) + 1e-5f);
  const float4* gp = (const float4*)g;
  const float4* bp = (const float4*)b;
  #pragma unroll
  for (int i = 0; i < 4; i++) {
    float4 gv = gp[lane+64*i], bv = bp[lane+64*i], o4;
    o4.x = (v[i].x-mu)*inv*gv.x + bv.x;
    o4.y = (v[i].y-mu)*inv*gv.y + bv.y;
    o4.z = (v[i].z-mu)*inv*gv.z + bv.z;
    o4.w = (v[i].w-mu)*inv*gv.w + bv.w;
    p[lane + 64*i] = o4;
  }
}

// ---------------- launch ----------------------------------------------------
extern "C" void kernel_launch(void* const* d_in, const int* in_sizes, int n_in,
                              void* d_out, int out_size, void* d_ws, size_t ws_size,
                              hipStream_t stream) {
  const float* x         = (const float*)d_in[0];
  const float* key_w     = (const float*)d_in[1];
  const float* out_w     = (const float*)d_in[2];
  const float* out_b     = (const float*)d_in[3];
  const float* gate_w    = (const float*)d_in[4];
  const float* gate_b    = (const float*)d_in[5];
  const float* ln_g      = (const float*)d_in[6];
  const float* ln_b      = (const float*)d_in[7];
  const float* pos_table = (const float*)d_in[8];
  const float* mem_keys  = (const float*)d_in[9];
  const float* mem_vals  = (const float*)d_in[10];
  const float* mem_age   = (const float*)d_in[11];
  const float* mem_conf  = (const float*)d_in[12];
  const int*   slot_order= (const int*)d_in[13];

  char* ws = (char*)d_ws;
  u16*   A    = (u16*)(ws + 0);            // combined bf16 [16384][2048]  64 MB
  u16*   Wcat = (u16*)(ws + 67108864);     // interleaved weights [2048][2048] 8 MB
  u16*   Wk   = (u16*)(ws + 75497472);     // key_w  bf16 [32][1024]       64 KB
  u16*   Vals = (u16*)(ws + 75563008);     // mem_vals bf16 [64][1024]    128 KB
  float* kwp  = (float*)(ws + 75694080);   // keys_with_pos [64][33]     8448 B
  float* biasv= (float*)(ws + 75702528);   // salience bias [64]
  float* y    = (float*)d_out;

  hipLaunchKernelGGL(k_prep,  dim3(1),    dim3(256), 0, stream,
                     mem_keys, pos_table, slot_order, mem_age, mem_conf,
                     key_w, mem_vals, kwp, biasv, Wk, Vals);
  hipLaunchKernelGGL(k_front, dim3(384),  dim3(256), 0, stream,
                     x, gate_w, out_w, Wk, Vals, kwp, biasv, A, Wcat);
  hipLaunchKernelGGL(k_gemm,  dim3(1024), dim3(512), 0, stream,
                     A, Wcat, out_b, gate_b, y);
  hipLaunchKernelGGL(k_ln,    dim3(4096), dim3(256), 0, stream, y, ln_g, ln_b);
}

// Round 10
// 292.360 us; speedup vs baseline: 1.0002x; 1.0002x over previous
//
#include <hip/hip_runtime.h>
#include <hip/hip_bf16.h>
#include <math.h>

// EpisodicMemory fused pipeline for MI355X (gfx950).
// B=16384, HID=1024, SLOTS=64, KD=32.
// Round 10: k_gemm = 256x256 tile / BK=64 / 1024 threads (16 waves of 64x64),
// single 64KB LDS buffer, 2 independent blocks/CU, both-sides chunk swizzle.
// Rationale: staged traffic (BM,BN)=(256,256) -> 1024MB vs (128,256)'s 1536MB;
// kernel is input-feed (L2/L3) bound, so traffic is the lever.

typedef float    f32x4 __attribute__((ext_vector_type(4)));
typedef short    s16x8 __attribute__((ext_vector_type(8)));
typedef unsigned short u16;
typedef unsigned short u16x8 __attribute__((ext_vector_type(8)));

#define MFMA_BF16(a,b,c) __builtin_amdgcn_mfma_f32_16x16x32_bf16((a),(b),(c),0,0,0)

__device__ __forceinline__ void async16(void* lds, const void* g) {
  __builtin_amdgcn_global_load_lds((const __attribute__((address_space(1))) void*)g,
                                   (__attribute__((address_space(3))) void*)lds, 16, 0, 0);
}

__device__ __forceinline__ u16 f2bf(float f) {
  unsigned u = __float_as_uint(f);
  u += 0x7fffu + ((u >> 16) & 1u);   // RNE
  return (u16)(u >> 16);
}
__device__ __forceinline__ float bf2f(u16 h) {
  return __uint_as_float(((unsigned)h) << 16);
}

// ---------------- K0: slot prep + key_w/mem_vals bf16 conversion ------------
__global__ __launch_bounds__(256) void k_prep(
    const float* __restrict__ mem_keys, const float* __restrict__ pos_table,
    const int* __restrict__ slot_order, const float* __restrict__ mem_age,
    const float* __restrict__ mem_conf, const float* __restrict__ key_w,
    const float* __restrict__ mem_vals,
    float* __restrict__ kwp /*[64][33]*/, float* __restrict__ biasv,
    u16* __restrict__ Wk, u16* __restrict__ Vals) {
  int tid = threadIdx.x;
  if (tid < 64) {                      // wave 0: per-slot salience + keys
    int s = tid;
    float age  = mem_age[s];
    float freq = fmaxf(age, 1.0f);
    float fm = freq;
    #pragma unroll
    for (int o = 32; o; o >>= 1) fm = fmaxf(fm, __shfl_xor(fm, o));
    float freq_norm = logf(freq + 1.0f) / (logf(fm + 2.0f) + 1e-8f);
    float recency = expf(-age * (1.0f/200.0f));
    biasv[s] = 0.2f*recency + 0.15f*freq_norm + 0.1f*mem_conf[s] + 0.08f;

    int idx = slot_order[s] & 63;
    float k[32]; float ss = 0.f;
    #pragma unroll
    for (int d = 0; d < 32; d++) {
      float v = mem_keys[s*32+d] + 0.1f*pos_table[idx*32+d];
      k[d] = v; ss += v*v;
    }
    float inv = 1.0f / fmaxf(sqrtf(ss), 1e-12f);
    #pragma unroll
    for (int d = 0; d < 32; d++) kwp[s*33+d] = k[d]*inv;
  }
  for (int g = tid; g < 8192; g += 256) {               // key_w -> bf16
    float4 v = ((const float4*)key_w)[g];
    ushort4 o; o.x=f2bf(v.x); o.y=f2bf(v.y); o.z=f2bf(v.z); o.w=f2bf(v.w);
    *(ushort4*)(Wk + (size_t)g*4) = o;
  }
  for (int g = tid; g < 16384; g += 256) {              // mem_vals -> bf16
    float4 v = ((const float4*)mem_vals)[g];
    ushort4 o; o.x=f2bf(v.x); o.y=f2bf(v.y); o.z=f2bf(v.z); o.w=f2bf(v.w);
    *(ushort4*)(Vals + (size_t)g*4) = o;
  }
}

// ---------------- K1: fused front (x->bf16, qk, softmax, retrieve) ----------
// blocks 0..255: 64 x-rows each. blocks 256..383: weight conversion.
__global__ __launch_bounds__(256) void k_front(
    const float* __restrict__ x, const float* __restrict__ gate_w,
    const float* __restrict__ out_w, const u16* __restrict__ Wk,
    const u16* __restrict__ Vals, const float* __restrict__ kwp,
    const float* __restrict__ biasv, u16* __restrict__ A,
    u16* __restrict__ Wcat) {
  const int b = blockIdx.x, tid = threadIdx.x;
  if (b >= 256) {
    // gate_w/out_w -> Wcat [2048][2048], row p=g*32+h*16+c <- (h?out:gate)[g*16+c]
    const int NW = 524288;   // float4 groups per weight
    for (int g = (b-256)*256 + tid; g < 2*NW; g += 128*256) {
      float4 v; int t, pb;
      if (g < NW) { t = g;      v = ((const float4*)gate_w)[t]; pb = 0; }
      else        { t = g - NW; v = ((const float4*)out_w)[t];  pb = 16; }
      int row = t >> 9, grp = t & 511;
      int p = ((row>>4)<<5) + pb + (row&15);
      ushort4 o; o.x=f2bf(v.x); o.y=f2bf(v.y); o.z=f2bf(v.z); o.w=f2bf(v.w);
      *(ushort4*)(Wcat + ((size_t)p*2048 + grp*4)) = o;
    }
    return;
  }

  __shared__ __align__(16) u16 sX[64*72];     // x tile bf16, padded stride 72
  __shared__ float sQK[64*33];
  __shared__ float sK[64*33];
  __shared__ float sBias[64];
  __shared__ float sQn[64*32];
  __shared__ float sAttn[64*64];

  const int lane = tid & 63, w = tid >> 6;
  const int ln15 = lane & 15, hi = lane >> 4;
  const size_t r0 = (size_t)b * 64;

  for (int i = tid; i < 64*33; i += 256) sK[i] = kwp[i];
  if (tid < 64) sBias[tid] = biasv[tid];

  // ---- qk = x @ key_w^T via MFMA, fused with x->bf16 conversion ----
  f32x4 acc0 = {0.f,0.f,0.f,0.f}, acc1 = {0.f,0.f,0.f,0.f};
  const int xrow = tid >> 4, xc4 = tid & 15;
  for (int k0 = 0; k0 < 1024; k0 += 64) {
    #pragma unroll
    for (int j = 0; j < 4; j++) {
      int row = xrow + j*16;
      float4 v = *(const float4*)&x[(r0+row)*1024 + k0 + xc4*4];
      ushort4 o; o.x=f2bf(v.x); o.y=f2bf(v.y); o.z=f2bf(v.z); o.w=f2bf(v.w);
      *(ushort4*)&sX[row*72 + xc4*4] = o;
      *(ushort4*)&A[(r0+row)*2048 + k0 + xc4*4] = o;    // combined left half
    }
    __syncthreads();
    #pragma unroll
    for (int kk = 0; kk < 2; kk++) {
      int kb = kk*32 + hi*8;
      s16x8 a  = *(const s16x8*)&sX[(w*16 + ln15)*72 + kb];
      s16x8 b0 = *(const s16x8*)&Wk[(size_t)ln15*1024 + k0 + kb];
      s16x8 b1 = *(const s16x8*)&Wk[(size_t)(16+ln15)*1024 + k0 + kb];
      acc0 = MFMA_BF16(a, b0, acc0);
      acc1 = MFMA_BF16(a, b1, acc1);
    }
    __syncthreads();
  }
  #pragma unroll
  for (int i = 0; i < 4; i++) {
    sQK[(w*16 + hi*4 + i)*33 + ln15]      = acc0[i];
    sQK[(w*16 + hi*4 + i)*33 + 16 + ln15] = acc1[i];
  }
  __syncthreads();

  // ---- softmax over 64 slots (wave handles its 16 rows) ----
  int d = lane & 31;
  for (int j = 0; j < 16; j++) {
    int rl = w*16 + j;
    float v = sQK[rl*33 + d];
    float sq = v*v;
    #pragma unroll
    for (int o = 16; o; o >>= 1) sq += __shfl_xor(sq, o);   // 32-group sum
    float qn = v / fmaxf(sqrtf(sq), 1e-12f);
    if (lane < 32) sQn[rl*32 + d] = qn;
    float accs = 0.f;
    #pragma unroll
    for (int dd = 0; dd < 32; dd++) accs += sK[lane*33+dd] * sQn[rl*32+dd];
    float sim = accs * 0.17677669529663687f;   // 1/sqrt(32)
    float sal = fminf(fmaxf(0.45f*sim + sBias[lane], 0.0f), 1.0f);
    float mx = sal;
    #pragma unroll
    for (int o = 32; o; o >>= 1) mx = fmaxf(mx, __shfl_xor(mx, o));
    float e = expf(sal - mx);
    float sm = e;
    #pragma unroll
    for (int o = 32; o; o >>= 1) sm += __shfl_xor(sm, o);
    sAttn[rl*64 + lane] = e / sm;
  }
  __syncthreads();

  // ---- retrieved = attn @ mem_vals; 4 sweeps of 16 rows ----
  for (int g = 0; g < 4; g++) {
    float acc[4][16];
    #pragma unroll
    for (int j = 0; j < 4; j++)
      #pragma unroll
      for (int i = 0; i < 16; i++) acc[j][i] = 0.f;
    const u16* vp = Vals + lane*16;
    for (int s = 0; s < 64; s++) {
      s16x8 v0 = *(const s16x8*)(vp + (size_t)s*1024);
      s16x8 v1 = *(const s16x8*)(vp + (size_t)s*1024 + 8);
      float vf[16];
      #pragma unroll
      for (int i = 0; i < 8; i++) { vf[i] = bf2f((u16)v0[i]); vf[8+i] = bf2f((u16)v1[i]); }
      #pragma unroll
      for (int j = 0; j < 4; j++) {
        float a = sAttn[(g*16 + w*4 + j)*64 + s];
        #pragma unroll
        for (int i = 0; i < 16; i++) acc[j][i] += a * vf[i];
      }
    }
    #pragma unroll
    for (int j = 0; j < 4; j++) {
      size_t r = r0 + g*16 + w*4 + j;
      u16x8 o0, o1;
      #pragma unroll
      for (int i = 0; i < 8; i++) { o0[i] = f2bf(acc[j][i]); o1[i] = f2bf(acc[j][8+i]); }
      u16* dst = A + r*2048 + 1024 + lane*16;
      *(u16x8*)dst = o0;
      *(u16x8*)(dst + 8) = o1;
    }
  }
}

// ---------------- K2: single interleaved GEMM + fused epilogue --------------
// C = combined[16384,2048] @ Wcat[2048,2048]^T.
// 256x256 tile, 16 waves (4x4, wave=64x64), BK=64, single 64KB LDS buffer,
// plain 2-barrier loop; 2 independent blocks/CU. Grid = 512 = one full wave.
__global__ __launch_bounds__(1024, 2) void k_gemm(
    const u16* __restrict__ A, const u16* __restrict__ Wcat,
    const float* __restrict__ out_b, const float* __restrict__ gate_b,
    float* __restrict__ y) {
  __shared__ __align__(16) u16 sA[16384];   // 256 rows x 64 (swizzled)
  __shared__ __align__(16) u16 sB[16384];   // 256 rows x 64 (swizzled)

  const int tid = threadIdx.x, lane = tid & 63, w = tid >> 6;
  const int ln15 = lane & 15, hi = lane >> 4, p7 = ln15 & 7;
  const int wm = w >> 2, wn = w & 3;        // 4x4 waves, wave = 64x64

  // 512 blocks: colblk = XCD (1MB B panel resident per XCD L2), rowblk swept
  const int colblk = blockIdx.x & 7;
  const int rowblk = blockIdx.x >> 3;       // 0..63
  const size_t r0 = (size_t)rowblk * 256;
  const size_t c0 = (size_t)colblk * 256;

  const u16* gA = A    + r0 * 2048;
  const u16* gB = Wcat + c0 * 2048;

  // staging: 2048 chunks of 16B per tile side, 2/thread each side; physical
  // chunk pc of row r holds logical chunk pc ^ (r&7) (inv-swz global source).
  int off[2];
  #pragma unroll
  for (int j = 0; j < 2; j++) {
    int c = tid + j*1024, row = c >> 3, pc = c & 7;
    off[j] = row*2048 + ((pc ^ (row & 7)) << 3);
  }

  const int ck0 = (hi ^ p7) * 8;          // kk=0: logical chunk hi
  const int ck1 = ((4 | hi) ^ p7) * 8;    // kk=1: logical chunk 4|hi
  const int arow = (wm*64 + ln15) * 64;   // + m*1024
  const int brow = (wn*64 + ln15) * 64;   // + n*1024

  f32x4 acc[4][4];
  #pragma unroll
  for (int m = 0; m < 4; m++)
    #pragma unroll
    for (int n = 0; n < 4; n++) acc[m][n] = {0.f, 0.f, 0.f, 0.f};

  for (int kt = 0; kt < 32; ++kt) {
    const int ko = kt * 64;
    #pragma unroll
    for (int j = 0; j < 2; j++) {
      async16(&sA[(tid + j*1024)*8], gA + off[j] + ko);
      async16(&sB[(tid + j*1024)*8], gB + off[j] + ko);
    }
    __syncthreads();   // drains vmcnt(0): staged tile visible to all waves
    #pragma unroll
    for (int kk = 0; kk < 2; kk++) {
      const int ck = kk ? ck1 : ck0;
      s16x8 af[4], bfr[4];
      #pragma unroll
      for (int m = 0; m < 4; m++) af[m]  = *(const s16x8*)&sA[arow + m*1024 + ck];
      #pragma unroll
      for (int n = 0; n < 4; n++) bfr[n] = *(const s16x8*)&sB[brow + n*1024 + ck];
      #pragma unroll
      for (int m = 0; m < 4; m++)
        #pragma unroll
        for (int n = 0; n < 4; n++)
          acc[m][n] = MFMA_BF16(af[m], bfr[n], acc[m][n]);
    }
    __syncthreads();   // tile fully consumed before next stage overwrites
  }

  // epilogue: Wcat row p = c0 + wn*64 + n*16 + ln15; n even=gate, odd=out,
  // ocol = colblk*128 + wn*32 + (n>>1)*16 + ln15. y pre-LN (f32, in d_out).
  #pragma unroll
  for (int s = 0; s < 2; s++) {
    int ocol = colblk*128 + wn*32 + s*16 + ln15;
    float gbv = gate_b[ocol], obv = out_b[ocol];
    #pragma unroll
    for (int m = 0; m < 4; m++) {
      #pragma unroll
      for (int i = 0; i < 4; i++) {
        size_t r = r0 + wm*64 + m*16 + hi*4 + i;
        float gg = acc[m][s*2+0][i] + gbv;
        float go = acc[m][s*2+1][i] + obv;
        float h  = 0.5f*go*(1.0f + erff(go*0.70710678118654752f));  // exact gelu
        float sg = 1.0f/(1.0f + __expf(-gg));
        float rv = bf2f(A[r*2048 + 1024 + ocol]);
        float xv = bf2f(A[r*2048 + ocol]);
        y[r*1024 + ocol] = h + sg*rv + (1.0f - sg)*xv;
      }
    }
  }
}

// ---------------- K3: LayerNorm in place (wave per row) ---------------------
__global__ __launch_bounds__(256) void k_ln(float* __restrict__ y, const float* __restrict__ g,
                                            const float* __restrict__ b) {
  int row  = blockIdx.x*4 + (threadIdx.x >> 6);
  int lane = threadIdx.x & 63;
  float4* p = (float4*)(y + (size_t)row*1024);
  float4 v[4];
  #pragma unroll
  for (int i = 0; i < 4; i++) v[i] = p[lane + 64*i];
  float s = 0.f;
  #pragma unroll
  for (int i = 0; i < 4; i++) s += v[i].x + v[i].y + v[i].z + v[i].w;
  #pragma unroll
  for (int o = 32; o; o >>= 1) s += __shfl_xor(s, o);
  float mu = s * (1.0f/1024.0f);
  float vs = 0.f;
  #pragma unroll
  for (int i = 0; i < 4; i++) {
    float d0 = v[i].x-mu, d1 = v[i].y-mu, d2 = v[i].z-mu, d3 = v[i].w-mu;
    vs += d0*d0 + d1*d1 + d2*d2 + d3*d3;
  }
  #pragma unroll
  for (int o = 32; o; o >>= 1) vs += __shfl_xor(vs, o);
  float inv = 1.0f / sqrtf(vs*(1.0f/1024.0f) + 1e-5f);
  const float4* gp = (const float4*)g;
  const float4* bp = (const float4*)b;
  #pragma unroll
  for (int i = 0; i < 4; i++) {
    float4 gv = gp[lane+64*i], bv = bp[lane+64*i], o4;
    o4.x = (v[i].x-mu)*inv*gv.x + bv.x;
    o4.y = (v[i].y-mu)*inv*gv.y + bv.y;
    o4.z = (v[i].z-mu)*inv*gv.z + bv.z;
    o4.w = (v[i].w-mu)*inv*gv.w + bv.w;
    p[lane + 64*i] = o4;
  }
}

// ---------------- launch ----------------------------------------------------
extern "C" void kernel_launch(void* const* d_in, const int* in_sizes, int n_in,
                              void* d_out, int out_size, void* d_ws, size_t ws_size,
                              hipStream_t stream) {
  const float* x         = (const float*)d_in[0];
  const float* key_w     = (const float*)d_in[1];
  const float* out_w     = (const float*)d_in[2];
  const float* out_b     = (const float*)d_in[3];
  const float* gate_w    = (const float*)d_in[4];
  const float* gate_b    = (const float*)d_in[5];
  const float* ln_g      = (const float*)d_in[6];
  const float* ln_b      = (const float*)d_in[7];
  const float* pos_table = (const float*)d_in[8];
  const float* mem_keys  = (const float*)d_in[9];
  const float* mem_vals  = (const float*)d_in[10];
  const float* mem_age   = (const float*)d_in[11];
  const float* mem_conf  = (const float*)d_in[12];
  const int*   slot_order= (const int*)d_in[13];

  char* ws = (char*)d_ws;
  u16*   A    = (u16*)(ws + 0);            // combined bf16 [16384][2048]  64 MB
  u16*   Wcat = (u16*)(ws + 67108864);     // interleaved weights [2048][2048] 8 MB
  u16*   Wk   = (u16*)(ws + 75497472);     // key_w  bf16 [32][1024]       64 KB
  u16*   Vals = (u16*)(ws + 75563008);     // mem_vals bf16 [64][1024]    128 KB
  float* kwp  = (float*)(ws + 75694080);   // keys_with_pos [64][33]     8448 B
  float* biasv= (float*)(ws + 75702528);   // salience bias [64]
  float* y    = (float*)d_out;

  hipLaunchKernelGGL(k_prep,  dim3(1),    dim3(256),  0, stream,
                     mem_keys, pos_table, slot_order, mem_age, mem_conf,
                     key_w, mem_vals, kwp, biasv, Wk, Vals);
  hipLaunchKernelGGL(k_front, dim3(384),  dim3(256),  0, stream,
                     x, gate_w, out_w, Wk, Vals, kwp, biasv, A, Wcat);
  hipLaunchKernelGGL(k_gemm,  dim3(512),  dim3(1024), 0, stream,
                     A, Wcat, out_b, gate_b, y);
  hipLaunchKernelGGL(k_ln,    dim3(4096), dim3(256),  0, stream, y, ln_g, ln_b);
}

// Round 11
// 226.408 us; speedup vs baseline: 1.2915x; 1.2913x over previous
//
#include <hip/hip_runtime.h>
#include <hip/hip_bf16.h>
#include <math.h>

// EpisodicMemory fused pipeline for MI355X (gfx950).
// B=16384, HID=1024, SLOTS=64, KD=32.
// Round 11 ALGEBRAIC RESTRUCTURE: combined@W^T = x@W_left^T + attn@PV^T where
// PV = mem_vals@W_right^T (precomputed, 64x1024 per weight). Main GEMM K:
// 2048 -> 1088 (17 K-tiles) + 1 retrieved K-tile (attn@Vcat for the blend).
// A_ext = [x_bf16 | attn] (16384x1088); Wcat_ext = [W_left | PV] (2048x1088,
// gate/out rows interleaved in 16-groups); Vcat[p][s] = mem_vals[s][ocol(p)].
// k_gemm: 128x256 tile, BK=64, 8 waves of 64x64, single 48KB LDS buffer,
// 2-barrier loop, both-sides chunk swizzle (0 bank conflicts).

typedef float    f32x4 __attribute__((ext_vector_type(4)));
typedef short    s16x8 __attribute__((ext_vector_type(8)));
typedef unsigned short u16;
typedef unsigned short u16x8 __attribute__((ext_vector_type(8)));

#define MFMA_BF16(a,b,c) __builtin_amdgcn_mfma_f32_16x16x32_bf16((a),(b),(c),0,0,0)

__device__ __forceinline__ void async16(void* lds, const void* g) {
  __builtin_amdgcn_global_load_lds((const __attribute__((address_space(1))) void*)g,
                                   (__attribute__((address_space(3))) void*)lds, 16, 0, 0);
}

__device__ __forceinline__ u16 f2bf(float f) {
  unsigned u = __float_as_uint(f);
  u += 0x7fffu + ((u >> 16) & 1u);   // RNE
  return (u16)(u >> 16);
}
__device__ __forceinline__ float bf2f(u16 h) {
  return __uint_as_float(((unsigned)h) << 16);
}
__device__ __forceinline__ int ocol_of(int p) { return ((p >> 5) << 4) + (p & 15); }

// ---------------- K0: prep (slots, Wk bf16, Vcat transpose, PV GEMM) --------
// block 0:      kwp/biasv + key_w->bf16
// blocks 1-64:  Vcat[p][s] = mem_vals[s][ocol(p)]  (2048x64 bf16)
// blocks 65-96: PV: Wcat_ext[p][1024+s] = sum_h W[ocol(p)][1024+h]*mem_vals[s][h]
__global__ __launch_bounds__(256) void k_prep(
    const float* __restrict__ mem_keys, const float* __restrict__ pos_table,
    const int* __restrict__ slot_order, const float* __restrict__ mem_age,
    const float* __restrict__ mem_conf, const float* __restrict__ key_w,
    const float* __restrict__ mem_vals, const float* __restrict__ gate_w,
    const float* __restrict__ out_w,
    float* __restrict__ kwp, float* __restrict__ biasv,
    u16* __restrict__ Wk, u16* __restrict__ Vcat, u16* __restrict__ Wcat) {
  const int b = blockIdx.x, tid = threadIdx.x;

  if (b == 0) {
    if (tid < 64) {
      int s = tid;
      float age  = mem_age[s];
      float freq = fmaxf(age, 1.0f);
      float fm = freq;
      #pragma unroll
      for (int o = 32; o; o >>= 1) fm = fmaxf(fm, __shfl_xor(fm, o));
      float freq_norm = logf(freq + 1.0f) / (logf(fm + 2.0f) + 1e-8f);
      float recency = expf(-age * (1.0f/200.0f));
      biasv[s] = 0.2f*recency + 0.15f*freq_norm + 0.1f*mem_conf[s] + 0.08f;

      int idx = slot_order[s] & 63;
      float k[32]; float ss = 0.f;
      #pragma unroll
      for (int d = 0; d < 32; d++) {
        float v = mem_keys[s*32+d] + 0.1f*pos_table[idx*32+d];
        k[d] = v; ss += v*v;
      }
      float inv = 1.0f / fmaxf(sqrtf(ss), 1e-12f);
      #pragma unroll
      for (int d = 0; d < 32; d++) kwp[s*33+d] = k[d]*inv;
    }
    for (int g = tid; g < 8192; g += 256) {   // key_w f32 -> bf16
      float4 v = ((const float4*)key_w)[g];
      ushort4 o; o.x=f2bf(v.x); o.y=f2bf(v.y); o.z=f2bf(v.z); o.w=f2bf(v.w);
      *(ushort4*)(Wk + (size_t)g*4) = o;
    }
    return;
  }

  if (b <= 64) {                               // Vcat transpose
    int p0 = (b-1) * 32;
    for (int e = tid; e < 32*64; e += 256) {
      int pl = e >> 6, s = e & 63;
      int p = p0 + pl;
      Vcat[(size_t)p*64 + s] = f2bf(mem_vals[(size_t)s*1024 + ocol_of(p)]);
    }
    return;
  }

  // PV mini-GEMM: 64 p-rows x 64 slots, K=1024 (right halves of gate/out_w)
  __shared__ __align__(16) u16 sW[64*80];
  __shared__ __align__(16) u16 sV[64*80];
  const int pb = (b-65) * 64;
  const int lane = tid & 63, w = tid >> 6;
  const int ln15 = lane & 15, hi = lane >> 4;
  f32x4 acc[4];
  #pragma unroll
  for (int n = 0; n < 4; n++) acc[n] = {0.f,0.f,0.f,0.f};

  for (int kt = 0; kt < 16; ++kt) {
    #pragma unroll
    for (int j = 0; j < 4; j++) {
      int idx = tid + j*256;
      int row = idx >> 4, g4 = idx & 15;
      int p = pb + row;
      const float* wsrc = ((p >> 4) & 1) ? out_w : gate_w;
      float4 v = *(const float4*)&wsrc[(size_t)ocol_of(p)*2048 + 1024 + kt*64 + g4*4];
      ushort4 o; o.x=f2bf(v.x); o.y=f2bf(v.y); o.z=f2bf(v.z); o.w=f2bf(v.w);
      *(ushort4*)&sW[row*80 + g4*4] = o;
      float4 u = *(const float4*)&mem_vals[(size_t)row*1024 + kt*64 + g4*4];
      ushort4 p2; p2.x=f2bf(u.x); p2.y=f2bf(u.y); p2.z=f2bf(u.z); p2.w=f2bf(u.w);
      *(ushort4*)&sV[row*80 + g4*4] = p2;
    }
    __syncthreads();
    #pragma unroll
    for (int kk = 0; kk < 2; kk++) {
      int kb = kk*32 + hi*8;
      s16x8 a = *(const s16x8*)&sW[(w*16 + ln15)*80 + kb];
      #pragma unroll
      for (int n = 0; n < 4; n++) {
        s16x8 bv = *(const s16x8*)&sV[(n*16 + ln15)*80 + kb];
        acc[n] = MFMA_BF16(a, bv, acc[n]);
      }
    }
    __syncthreads();
  }
  #pragma unroll
  for (int n = 0; n < 4; n++)
    #pragma unroll
    for (int i = 0; i < 4; i++) {
      int p = pb + w*16 + hi*4 + i;
      Wcat[(size_t)p*1088 + 1024 + n*16 + ln15] = f2bf(acc[n][i]);
    }
}

// ---------------- K1: fused front (x->bf16, qk, softmax, attn->A_ext) -------
// blocks 0..255: 64 x-rows each. blocks 256..287: weight LEFT-half conversion.
__global__ __launch_bounds__(256) void k_front(
    const float* __restrict__ x, const float* __restrict__ gate_w,
    const float* __restrict__ out_w, const u16* __restrict__ Wk,
    const float* __restrict__ kwp, const float* __restrict__ biasv,
    u16* __restrict__ A, u16* __restrict__ Wcat) {
  const int b = blockIdx.x, tid = threadIdx.x;
  if (b >= 256) {
    // left halves -> Wcat_ext[p][0..1023]; 2x262144 float4 groups
    for (int g = (b-256)*256 + tid; g < 524288; g += 32*256) {
      float4 v; int t, pb;
      if (g < 262144) { t = g;          v = *(const float4*)&gate_w[(size_t)(t>>8)*2048 + (t&255)*4]; pb = 0; }
      else            { t = g - 262144; v = *(const float4*)&out_w [(size_t)(t>>8)*2048 + (t&255)*4]; pb = 16; }
      int row = t >> 8, grp = t & 255;
      int p = ((row>>4)<<5) + pb + (row&15);
      ushort4 o; o.x=f2bf(v.x); o.y=f2bf(v.y); o.z=f2bf(v.z); o.w=f2bf(v.w);
      *(ushort4*)(Wcat + ((size_t)p*1088 + grp*4)) = o;
    }
    return;
  }

  __shared__ __align__(16) u16 sX[64*72];     // x tile bf16, padded stride 72
  __shared__ float sQK[64*33];
  __shared__ float sK[64*33];
  __shared__ float sBias[64];
  __shared__ float sQn[64*32];

  const int lane = tid & 63, w = tid >> 6;
  const int ln15 = lane & 15, hi = lane >> 4;
  const size_t r0 = (size_t)b * 64;

  for (int i = tid; i < 64*33; i += 256) sK[i] = kwp[i];
  if (tid < 64) sBias[tid] = biasv[tid];

  // ---- qk = x @ key_w^T via MFMA, fused with x->bf16 conversion ----
  f32x4 acc0 = {0.f,0.f,0.f,0.f}, acc1 = {0.f,0.f,0.f,0.f};
  const int xrow = tid >> 4, xc4 = tid & 15;
  for (int k0 = 0; k0 < 1024; k0 += 64) {
    #pragma unroll
    for (int j = 0; j < 4; j++) {
      int row = xrow + j*16;
      float4 v = *(const float4*)&x[(r0+row)*1024 + k0 + xc4*4];
      ushort4 o; o.x=f2bf(v.x); o.y=f2bf(v.y); o.z=f2bf(v.z); o.w=f2bf(v.w);
      *(ushort4*)&sX[row*72 + xc4*4] = o;
      *(ushort4*)&A[(r0+row)*1088 + k0 + xc4*4] = o;    // A_ext left (x bf16)
    }
    __syncthreads();
    #pragma unroll
    for (int kk = 0; kk < 2; kk++) {
      int kb = kk*32 + hi*8;
      s16x8 a  = *(const s16x8*)&sX[(w*16 + ln15)*72 + kb];
      s16x8 b0 = *(const s16x8*)&Wk[(size_t)ln15*1024 + k0 + kb];
      s16x8 b1 = *(const s16x8*)&Wk[(size_t)(16+ln15)*1024 + k0 + kb];
      acc0 = MFMA_BF16(a, b0, acc0);
      acc1 = MFMA_BF16(a, b1, acc1);
    }
    __syncthreads();
  }
  #pragma unroll
  for (int i = 0; i < 4; i++) {
    sQK[(w*16 + hi*4 + i)*33 + ln15]      = acc0[i];
    sQK[(w*16 + hi*4 + i)*33 + 16 + ln15] = acc1[i];
  }
  __syncthreads();

  // ---- softmax over 64 slots; write attn bf16 to A_ext[1024..1087] ----
  int d = lane & 31;
  for (int j = 0; j < 16; j++) {
    int rl = w*16 + j;
    float v = sQK[rl*33 + d];
    float sq = v*v;
    #pragma unroll
    for (int o = 16; o; o >>= 1) sq += __shfl_xor(sq, o);   // 32-group sum
    float qn = v / fmaxf(sqrtf(sq), 1e-12f);
    if (lane < 32) sQn[rl*32 + d] = qn;
    float accs = 0.f;
    #pragma unroll
    for (int dd = 0; dd < 32; dd++) accs += sK[lane*33+dd] * sQn[rl*32+dd];
    float sim = accs * 0.17677669529663687f;   // 1/sqrt(32)
    float sal = fminf(fmaxf(0.45f*sim + sBias[lane], 0.0f), 1.0f);
    float mx = sal;
    #pragma unroll
    for (int o = 32; o; o >>= 1) mx = fmaxf(mx, __shfl_xor(mx, o));
    float e = expf(sal - mx);
    float sm = e;
    #pragma unroll
    for (int o = 32; o; o >>= 1) sm += __shfl_xor(sm, o);
    A[(r0 + rl)*1088 + 1024 + lane] = f2bf(e / sm);
  }
}

// ---------------- K2: GEMM (K=1088 + retrieved tile) + fused epilogue -------
// C = A_ext[16384,1088] @ Wcat_ext[2048,1088]^T  (gate/out interleaved),
// then one extra K-tile: acc_r = attn-tile @ Vcat-slice = retrieved values.
// 128x256 tile, 8 waves (2x4, wave 64x64), BK=64, single 48KB LDS buffer.
__global__ __launch_bounds__(512, 2) void k_gemm(
    const u16* __restrict__ A, const u16* __restrict__ Wcat,
    const u16* __restrict__ Vcat, const float* __restrict__ out_b,
    const float* __restrict__ gate_b, float* __restrict__ y) {
  __shared__ __align__(16) u16 sA[8192];    // 128 rows x 64 (swizzled)
  __shared__ __align__(16) u16 sB[16384];   // 256 rows x 64 (swizzled)

  const int tid = threadIdx.x, lane = tid & 63, w = tid >> 6;
  const int ln15 = lane & 15, hi = lane >> 4, p7 = ln15 & 7;
  const int wm = w >> 2, wn = w & 3;        // 2x4 waves, wave = 64x64

  const int colblk = blockIdx.x & 7;        // XCD-resident weight panel
  const int rowblk = blockIdx.x >> 3;
  const size_t r0 = (size_t)rowblk * 128;
  const size_t c0 = (size_t)colblk * 256;

  const u16* gA = A    + r0 * 1088;
  const u16* gB = Wcat + c0 * 1088;
  const u16* gV = Vcat + c0 * 64;

  // staging: A 1024 chunks (2/thread), B 2048 chunks (4/thread); physical
  // chunk pc of row r holds logical chunk pc ^ (r&7) (inv-swz global source).
  int offA[2], offB[4], offV[4];
  #pragma unroll
  for (int j = 0; j < 2; j++) {
    int c = tid + j*512, row = c >> 3, pc = c & 7;
    offA[j] = row*1088 + ((pc ^ (row & 7)) << 3);
  }
  #pragma unroll
  for (int j = 0; j < 4; j++) {
    int c = tid + j*512, row = c >> 3, pc = c & 7;
    offB[j] = row*1088 + ((pc ^ (row & 7)) << 3);
    offV[j] = row*64   + ((pc ^ (row & 7)) << 3);
  }

  const int ck0 = (hi ^ p7) * 8;            // kk=0: logical chunk hi
  const int ck1 = ((4 | hi) ^ p7) * 8;      // kk=1: logical chunk 4|hi
  const int arow = (wm*64 + ln15) * 64;     // + m*1024
  const int brow = (wn*64 + ln15) * 64;     // + n*1024

  f32x4 acc[4][4], accr[4][2];
  #pragma unroll
  for (int m = 0; m < 4; m++) {
    #pragma unroll
    for (int n = 0; n < 4; n++) acc[m][n] = {0.f, 0.f, 0.f, 0.f};
    accr[m][0] = {0.f,0.f,0.f,0.f}; accr[m][1] = {0.f,0.f,0.f,0.f};
  }

  #pragma unroll 1
  for (int kt = 0; kt < 17; ++kt) {
    const int ko = kt * 64;
    #pragma unroll
    for (int j = 0; j < 2; j++) async16(&sA[(tid + j*512)*8], gA + offA[j] + ko);
    #pragma unroll
    for (int j = 0; j < 4; j++) async16(&sB[(tid + j*512)*8], gB + offB[j] + ko);
    __syncthreads();
    #pragma unroll
    for (int kk = 0; kk < 2; kk++) {
      const int ck = kk ? ck1 : ck0;
      s16x8 af[4], bfr[4];
      #pragma unroll
      for (int m = 0; m < 4; m++) af[m]  = *(const s16x8*)&sA[arow + m*1024 + ck];
      #pragma unroll
      for (int n = 0; n < 4; n++) bfr[n] = *(const s16x8*)&sB[brow + n*1024 + ck];
      #pragma unroll
      for (int m = 0; m < 4; m++)
        #pragma unroll
        for (int n = 0; n < 4; n++)
          acc[m][n] = MFMA_BF16(af[m], bfr[n], acc[m][n]);
    }
    __syncthreads();   // tile fully consumed before next stage overwrites
  }

  // retrieved pass: sA still holds kt=16 (attn tile); stage Vcat slice -> sB
  #pragma unroll
  for (int j = 0; j < 4; j++) async16(&sB[(tid + j*512)*8], gV + offV[j]);
  __syncthreads();
  #pragma unroll
  for (int kk = 0; kk < 2; kk++) {
    const int ck = kk ? ck1 : ck0;
    s16x8 af[4], bf0, bf1;
    #pragma unroll
    for (int m = 0; m < 4; m++) af[m] = *(const s16x8*)&sA[arow + m*1024 + ck];
    bf0 = *(const s16x8*)&sB[brow + ck];            // n-tile 0 (gate slot s=0)
    bf1 = *(const s16x8*)&sB[brow + 2*1024 + ck];   // n-tile 2 (gate slot s=1)
    #pragma unroll
    for (int m = 0; m < 4; m++) {
      accr[m][0] = MFMA_BF16(af[m], bf0, accr[m][0]);
      accr[m][1] = MFMA_BF16(af[m], bf1, accr[m][1]);
    }
  }

  // epilogue: acc[m][2s]=gate_pre, acc[m][2s+1]=out_pre, accr[m][s]=retrieved
  #pragma unroll
  for (int s = 0; s < 2; s++) {
    int ocol = colblk*128 + wn*32 + s*16 + ln15;
    float gbv = gate_b[ocol], obv = out_b[ocol];
    #pragma unroll
    for (int m = 0; m < 4; m++) {
      #pragma unroll
      for (int i = 0; i < 4; i++) {
        size_t r = r0 + wm*64 + m*16 + hi*4 + i;
        float gg = acc[m][s*2+0][i] + gbv;
        float go = acc[m][s*2+1][i] + obv;
        float h  = 0.5f*go*(1.0f + erff(go*0.70710678118654752f));  // exact gelu
        float sg = 1.0f/(1.0f + __expf(-gg));
        float rv = accr[m][s][i];
        float xv = bf2f(A[r*1088 + ocol]);
        y[r*1024 + ocol] = h + sg*rv + (1.0f - sg)*xv;
      }
    }
  }
}

// ---------------- K3: LayerNorm in place (wave per row) ---------------------
__global__ __launch_bounds__(256) void k_ln(float* __restrict__ y, const float* __restrict__ g,
                                            const float* __restrict__ b) {
  int row  = blockIdx.x*4 + (threadIdx.x >> 6);
  int lane = threadIdx.x & 63;
  float4* p = (float4*)(y + (size_t)row*1024);
  float4 v[4];
  #pragma unroll
  for (int i = 0; i < 4; i++) v[i] = p[lane + 64*i];
  float s = 0.f;
  #pragma unroll
  for (int i = 0; i < 4; i++) s += v[i].x + v[i].y + v[i].z + v[i].w;
  #pragma unroll
  for (int o = 32; o; o >>= 1) s += __shfl_xor(s, o);
  float mu = s * (1.0f/1024.0f);
  float vs = 0.f;
  #pragma unroll
  for (int i = 0; i < 4; i++) {
    float d0 = v[i].x-mu, d1 = v[i].y-mu, d2 = v[i].z-mu, d3 = v[i].w-mu;
    vs += d0*d0 + d1*d1 + d2*d2 + d3*d3;
  }
  #pragma unroll
  for (int o = 32; o; o >>= 1) vs += __shfl_xor(vs, o);
  float inv = 1.0f / sqrtf(vs*(1.0f/1024.0f) + 1e-5f);
  const float4* gp = (const float4*)g;
  const float4* bp = (const float4*)b;
  #pragma unroll
  for (int i = 0; i < 4; i++) {
    float4 gv = gp[lane+64*i], bv = bp[lane+64*i], o4;
    o4.x = (v[i].x-mu)*inv*gv.x + bv.x;
    o4.y = (v[i].y-mu)*inv*gv.y + bv.y;
    o4.z = (v[i].z-mu)*inv*gv.z + bv.z;
    o4.w = (v[i].w-mu)*inv*gv.w + bv.w;
    p[lane + 64*i] = o4;
  }
}

// ---------------- launch ----------------------------------------------------
extern "C" void kernel_launch(void* const* d_in, const int* in_sizes, int n_in,
                              void* d_out, int out_size, void* d_ws, size_t ws_size,
                              hipStream_t stream) {
  const float* x         = (const float*)d_in[0];
  const float* key_w     = (const float*)d_in[1];
  const float* out_w     = (const float*)d_in[2];
  const float* out_b     = (const float*)d_in[3];
  const float* gate_w    = (const float*)d_in[4];
  const float* gate_b    = (const float*)d_in[5];
  const float* ln_g      = (const float*)d_in[6];
  const float* ln_b      = (const float*)d_in[7];
  const float* pos_table = (const float*)d_in[8];
  const float* mem_keys  = (const float*)d_in[9];
  const float* mem_vals  = (const float*)d_in[10];
  const float* mem_age   = (const float*)d_in[11];
  const float* mem_conf  = (const float*)d_in[12];
  const int*   slot_order= (const int*)d_in[13];

  char* ws = (char*)d_ws;
  u16*   A    = (u16*)(ws + 0);            // A_ext bf16 [16384][1088]  35.7 MB
  u16*   Wcat = (u16*)(ws + 36700160);     // Wcat_ext bf16 [2048][1088] 4.5 MB
  u16*   Vcat = (u16*)(ws + 41943040);     // Vcat bf16 [2048][64]     256 KB
  u16*   Wk   = (u16*)(ws + 42205184);     // key_w bf16 [32][1024]     64 KB
  float* kwp  = (float*)(ws + 42270720);   // keys_with_pos [64][33]   8448 B
  float* biasv= (float*)(ws + 42279168);   // salience bias [64]
  float* y    = (float*)d_out;

  hipLaunchKernelGGL(k_prep,  dim3(97),   dim3(256), 0, stream,
                     mem_keys, pos_table, slot_order, mem_age, mem_conf,
                     key_w, mem_vals, gate_w, out_w, kwp, biasv, Wk, Vcat, Wcat);
  hipLaunchKernelGGL(k_front, dim3(288),  dim3(256), 0, stream,
                     x, gate_w, out_w, Wk, kwp, biasv, A, Wcat);
  hipLaunchKernelGGL(k_gemm,  dim3(1024), dim3(512), 0, stream,
                     A, Wcat, Vcat, out_b, gate_b, y);
  hipLaunchKernelGGL(k_ln,    dim3(4096), dim3(256), 0, stream, y, ln_g, ln_b);
}

// Round 12
// 188.003 us; speedup vs baseline: 1.5554x; 1.2043x over previous
//
#include <hip/hip_runtime.h>
#include <hip/hip_bf16.h>
#include <math.h>

// EpisodicMemory fused pipeline for MI355X (gfx950).
// B=16384, HID=1024, SLOTS=64, KD=32.
// Round 12: algebraic restructure (combined@W^T = x@W_left^T + attn@PV^T,
// K=1088 + 1 retrieved tile) in the round-10 GEMM geometry: 256x256 tile,
// 1024 threads (16 waves of 64x64), BK=64, single 64KB LDS buffer,
// launch_bounds(1024,2), 2-barrier loop, both-sides chunk swizzle.

typedef float    f32x4 __attribute__((ext_vector_type(4)));
typedef short    s16x8 __attribute__((ext_vector_type(8)));
typedef unsigned short u16;
typedef unsigned short u16x8 __attribute__((ext_vector_type(8)));

#define MFMA_BF16(a,b,c) __builtin_amdgcn_mfma_f32_16x16x32_bf16((a),(b),(c),0,0,0)

__device__ __forceinline__ void async16(void* lds, const void* g) {
  __builtin_amdgcn_global_load_lds((const __attribute__((address_space(1))) void*)g,
                                   (__attribute__((address_space(3))) void*)lds, 16, 0, 0);
}

__device__ __forceinline__ u16 f2bf(float f) {
  unsigned u = __float_as_uint(f);
  u += 0x7fffu + ((u >> 16) & 1u);   // RNE
  return (u16)(u >> 16);
}
__device__ __forceinline__ float bf2f(u16 h) {
  return __uint_as_float(((unsigned)h) << 16);
}
__device__ __forceinline__ int ocol_of(int p) { return ((p >> 5) << 4) + (p & 15); }

// ---------------- K0: prep (slots, Wk bf16, Vcat transpose, PV GEMM) --------
// block 0:      kwp/biasv + key_w->bf16
// blocks 1-64:  Vcat[p][s] = mem_vals[s][ocol(p)]  (2048x64 bf16)
// blocks 65-96: PV: Wcat_ext[p][1024+s] = sum_h W[ocol(p)][1024+h]*mem_vals[s][h]
__global__ __launch_bounds__(256) void k_prep(
    const float* __restrict__ mem_keys, const float* __restrict__ pos_table,
    const int* __restrict__ slot_order, const float* __restrict__ mem_age,
    const float* __restrict__ mem_conf, const float* __restrict__ key_w,
    const float* __restrict__ mem_vals, const float* __restrict__ gate_w,
    const float* __restrict__ out_w,
    float* __restrict__ kwp, float* __restrict__ biasv,
    u16* __restrict__ Wk, u16* __restrict__ Vcat, u16* __restrict__ Wcat) {
  const int b = blockIdx.x, tid = threadIdx.x;

  if (b == 0) {
    if (tid < 64) {
      int s = tid;
      float age  = mem_age[s];
      float freq = fmaxf(age, 1.0f);
      float fm = freq;
      #pragma unroll
      for (int o = 32; o; o >>= 1) fm = fmaxf(fm, __shfl_xor(fm, o));
      float freq_norm = logf(freq + 1.0f) / (logf(fm + 2.0f) + 1e-8f);
      float recency = expf(-age * (1.0f/200.0f));
      biasv[s] = 0.2f*recency + 0.15f*freq_norm + 0.1f*mem_conf[s] + 0.08f;

      int idx = slot_order[s] & 63;
      float k[32]; float ss = 0.f;
      #pragma unroll
      for (int d = 0; d < 32; d++) {
        float v = mem_keys[s*32+d] + 0.1f*pos_table[idx*32+d];
        k[d] = v; ss += v*v;
      }
      float inv = 1.0f / fmaxf(sqrtf(ss), 1e-12f);
      #pragma unroll
      for (int d = 0; d < 32; d++) kwp[s*33+d] = k[d]*inv;
    }
    for (int g = tid; g < 8192; g += 256) {   // key_w f32 -> bf16
      float4 v = ((const float4*)key_w)[g];
      ushort4 o; o.x=f2bf(v.x); o.y=f2bf(v.y); o.z=f2bf(v.z); o.w=f2bf(v.w);
      *(ushort4*)(Wk + (size_t)g*4) = o;
    }
    return;
  }

  if (b <= 64) {                               // Vcat transpose
    int p0 = (b-1) * 32;
    for (int e = tid; e < 32*64; e += 256) {
      int pl = e >> 6, s = e & 63;
      int p = p0 + pl;
      Vcat[(size_t)p*64 + s] = f2bf(mem_vals[(size_t)s*1024 + ocol_of(p)]);
    }
    return;
  }

  // PV mini-GEMM: 64 p-rows x 64 slots, K=1024 (right halves of gate/out_w)
  __shared__ __align__(16) u16 sW[64*80];
  __shared__ __align__(16) u16 sV[64*80];
  const int pb = (b-65) * 64;
  const int lane = tid & 63, w = tid >> 6;
  const int ln15 = lane & 15, hi = lane >> 4;
  f32x4 acc[4];
  #pragma unroll
  for (int n = 0; n < 4; n++) acc[n] = {0.f,0.f,0.f,0.f};

  for (int kt = 0; kt < 16; ++kt) {
    #pragma unroll
    for (int j = 0; j < 4; j++) {
      int idx = tid + j*256;
      int row = idx >> 4, g4 = idx & 15;
      int p = pb + row;
      const float* wsrc = ((p >> 4) & 1) ? out_w : gate_w;
      float4 v = *(const float4*)&wsrc[(size_t)ocol_of(p)*2048 + 1024 + kt*64 + g4*4];
      ushort4 o; o.x=f2bf(v.x); o.y=f2bf(v.y); o.z=f2bf(v.z); o.w=f2bf(v.w);
      *(ushort4*)&sW[row*80 + g4*4] = o;
      float4 u = *(const float4*)&mem_vals[(size_t)row*1024 + kt*64 + g4*4];
      ushort4 p2; p2.x=f2bf(u.x); p2.y=f2bf(u.y); p2.z=f2bf(u.z); p2.w=f2bf(u.w);
      *(ushort4*)&sV[row*80 + g4*4] = p2;
    }
    __syncthreads();
    #pragma unroll
    for (int kk = 0; kk < 2; kk++) {
      int kb = kk*32 + hi*8;
      s16x8 a = *(const s16x8*)&sW[(w*16 + ln15)*80 + kb];
      #pragma unroll
      for (int n = 0; n < 4; n++) {
        s16x8 bv = *(const s16x8*)&sV[(n*16 + ln15)*80 + kb];
        acc[n] = MFMA_BF16(a, bv, acc[n]);
      }
    }
    __syncthreads();
  }
  #pragma unroll
  for (int n = 0; n < 4; n++)
    #pragma unroll
    for (int i = 0; i < 4; i++) {
      int p = pb + w*16 + hi*4 + i;
      Wcat[(size_t)p*1088 + 1024 + n*16 + ln15] = f2bf(acc[n][i]);
    }
}

// ---------------- K1: fused front (x->bf16, qk, softmax, attn->A_ext) -------
// blocks 0..255: 64 x-rows each. blocks 256..287: weight LEFT-half conversion.
__global__ __launch_bounds__(256) void k_front(
    const float* __restrict__ x, const float* __restrict__ gate_w,
    const float* __restrict__ out_w, const u16* __restrict__ Wk,
    const float* __restrict__ kwp, const float* __restrict__ biasv,
    u16* __restrict__ A, u16* __restrict__ Wcat) {
  const int b = blockIdx.x, tid = threadIdx.x;
  if (b >= 256) {
    // left halves -> Wcat_ext[p][0..1023]; 2x262144 float4 groups
    for (int g = (b-256)*256 + tid; g < 524288; g += 32*256) {
      float4 v; int t, pb;
      if (g < 262144) { t = g;          v = *(const float4*)&gate_w[(size_t)(t>>8)*2048 + (t&255)*4]; pb = 0; }
      else            { t = g - 262144; v = *(const float4*)&out_w [(size_t)(t>>8)*2048 + (t&255)*4]; pb = 16; }
      int row = t >> 8, grp = t & 255;
      int p = ((row>>4)<<5) + pb + (row&15);
      ushort4 o; o.x=f2bf(v.x); o.y=f2bf(v.y); o.z=f2bf(v.z); o.w=f2bf(v.w);
      *(ushort4*)(Wcat + ((size_t)p*1088 + grp*4)) = o;
    }
    return;
  }

  __shared__ __align__(16) u16 sX[64*72];     // x tile bf16, padded stride 72
  __shared__ float sQK[64*33];
  __shared__ float sK[64*33];
  __shared__ float sBias[64];
  __shared__ float sQn[64*32];

  const int lane = tid & 63, w = tid >> 6;
  const int ln15 = lane & 15, hi = lane >> 4;
  const size_t r0 = (size_t)b * 64;

  for (int i = tid; i < 64*33; i += 256) sK[i] = kwp[i];
  if (tid < 64) sBias[tid] = biasv[tid];

  // ---- qk = x @ key_w^T via MFMA, fused with x->bf16 conversion ----
  f32x4 acc0 = {0.f,0.f,0.f,0.f}, acc1 = {0.f,0.f,0.f,0.f};
  const int xrow = tid >> 4, xc4 = tid & 15;
  for (int k0 = 0; k0 < 1024; k0 += 64) {
    #pragma unroll
    for (int j = 0; j < 4; j++) {
      int row = xrow + j*16;
      float4 v = *(const float4*)&x[(r0+row)*1024 + k0 + xc4*4];
      ushort4 o; o.x=f2bf(v.x); o.y=f2bf(v.y); o.z=f2bf(v.z); o.w=f2bf(v.w);
      *(ushort4*)&sX[row*72 + xc4*4] = o;
      *(ushort4*)&A[(r0+row)*1088 + k0 + xc4*4] = o;    // A_ext left (x bf16)
    }
    __syncthreads();
    #pragma unroll
    for (int kk = 0; kk < 2; kk++) {
      int kb = kk*32 + hi*8;
      s16x8 a  = *(const s16x8*)&sX[(w*16 + ln15)*72 + kb];
      s16x8 b0 = *(const s16x8*)&Wk[(size_t)ln15*1024 + k0 + kb];
      s16x8 b1 = *(const s16x8*)&Wk[(size_t)(16+ln15)*1024 + k0 + kb];
      acc0 = MFMA_BF16(a, b0, acc0);
      acc1 = MFMA_BF16(a, b1, acc1);
    }
    __syncthreads();
  }
  #pragma unroll
  for (int i = 0; i < 4; i++) {
    sQK[(w*16 + hi*4 + i)*33 + ln15]      = acc0[i];
    sQK[(w*16 + hi*4 + i)*33 + 16 + ln15] = acc1[i];
  }
  __syncthreads();

  // ---- softmax over 64 slots; write attn bf16 to A_ext[1024..1087] ----
  int d = lane & 31;
  for (int j = 0; j < 16; j++) {
    int rl = w*16 + j;
    float v = sQK[rl*33 + d];
    float sq = v*v;
    #pragma unroll
    for (int o = 16; o; o >>= 1) sq += __shfl_xor(sq, o);   // 32-group sum
    float qn = v / fmaxf(sqrtf(sq), 1e-12f);
    if (lane < 32) sQn[rl*32 + d] = qn;
    float accs = 0.f;
    #pragma unroll
    for (int dd = 0; dd < 32; dd++) accs += sK[lane*33+dd] * sQn[rl*32+dd];
    float sim = accs * 0.17677669529663687f;   // 1/sqrt(32)
    float sal = fminf(fmaxf(0.45f*sim + sBias[lane], 0.0f), 1.0f);
    float mx = sal;
    #pragma unroll
    for (int o = 32; o; o >>= 1) mx = fmaxf(mx, __shfl_xor(mx, o));
    float e = expf(sal - mx);
    float sm = e;
    #pragma unroll
    for (int o = 32; o; o >>= 1) sm += __shfl_xor(sm, o);
    A[(r0 + rl)*1088 + 1024 + lane] = f2bf(e / sm);
  }
}

// ---------------- K2: GEMM (K=1088 + retrieved tile) + fused epilogue -------
// C = A_ext[16384,1088] @ Wcat_ext[2048,1088]^T  (gate/out interleaved),
// then one extra K-tile: acc_r = attn-tile @ Vcat-slice = retrieved values.
// 256x256 tile, 16 waves (4x4, wave 64x64), BK=64, single 64KB LDS buffer.
__global__ __launch_bounds__(1024, 2) void k_gemm(
    const u16* __restrict__ A, const u16* __restrict__ Wcat,
    const u16* __restrict__ Vcat, const float* __restrict__ out_b,
    const float* __restrict__ gate_b, float* __restrict__ y) {
  __shared__ __align__(16) u16 sA[16384];   // 256 rows x 64 (swizzled)
  __shared__ __align__(16) u16 sB[16384];   // 256 rows x 64 (swizzled)

  const int tid = threadIdx.x, lane = tid & 63, w = tid >> 6;
  const int ln15 = lane & 15, hi = lane >> 4, p7 = ln15 & 7;
  const int wm = w >> 2, wn = w & 3;        // 4x4 waves, wave = 64x64

  const int colblk = blockIdx.x & 7;        // XCD-resident weight panel
  const int rowblk = blockIdx.x >> 3;       // 0..63
  const size_t r0 = (size_t)rowblk * 256;
  const size_t c0 = (size_t)colblk * 256;

  const u16* gA = A    + r0 * 1088;
  const u16* gB = Wcat + c0 * 1088;
  const u16* gV = Vcat + c0 * 64;

  // staging: 2048 chunks of 16B per side, 2/thread each; physical chunk pc
  // of row r holds logical chunk pc ^ (r&7) (inverse swizzle on global src).
  int offA[2], offB[2], offV[2];
  #pragma unroll
  for (int j = 0; j < 2; j++) {
    int c = tid + j*1024, row = c >> 3, pc = c & 7;
    int sw = ((pc ^ (row & 7)) << 3);
    offA[j] = row*1088 + sw;
    offB[j] = row*1088 + sw;
    offV[j] = row*64   + sw;
  }

  const int ck0 = (hi ^ p7) * 8;            // kk=0: logical chunk hi
  const int ck1 = ((4 | hi) ^ p7) * 8;      // kk=1: logical chunk 4|hi
  const int arow = (wm*64 + ln15) * 64;     // + m*1024
  const int brow = (wn*64 + ln15) * 64;     // + n*1024

  f32x4 acc[4][4], accr[4][2];
  #pragma unroll
  for (int m = 0; m < 4; m++) {
    #pragma unroll
    for (int n = 0; n < 4; n++) acc[m][n] = {0.f, 0.f, 0.f, 0.f};
    accr[m][0] = {0.f,0.f,0.f,0.f}; accr[m][1] = {0.f,0.f,0.f,0.f};
  }

  #pragma unroll 1
  for (int kt = 0; kt < 17; ++kt) {
    const int ko = kt * 64;
    #pragma unroll
    for (int j = 0; j < 2; j++) {
      async16(&sA[(tid + j*1024)*8], gA + offA[j] + ko);
      async16(&sB[(tid + j*1024)*8], gB + offB[j] + ko);
    }
    __syncthreads();   // drains vmcnt(0): staged tile visible to all waves
    #pragma unroll
    for (int kk = 0; kk < 2; kk++) {
      const int ck = kk ? ck1 : ck0;
      s16x8 af[4], bfr[4];
      #pragma unroll
      for (int m = 0; m < 4; m++) af[m]  = *(const s16x8*)&sA[arow + m*1024 + ck];
      #pragma unroll
      for (int n = 0; n < 4; n++) bfr[n] = *(const s16x8*)&sB[brow + n*1024 + ck];
      #pragma unroll
      for (int m = 0; m < 4; m++)
        #pragma unroll
        for (int n = 0; n < 4; n++)
          acc[m][n] = MFMA_BF16(af[m], bfr[n], acc[m][n]);
    }
    __syncthreads();   // tile fully consumed before next stage overwrites
  }

  // retrieved pass: sA still holds kt=16 (attn tile); stage Vcat slice -> sB
  #pragma unroll
  for (int j = 0; j < 2; j++) async16(&sB[(tid + j*1024)*8], gV + offV[j]);
  __syncthreads();
  #pragma unroll
  for (int kk = 0; kk < 2; kk++) {
    const int ck = kk ? ck1 : ck0;
    s16x8 af[4], bf0, bf1;
    #pragma unroll
    for (int m = 0; m < 4; m++) af[m] = *(const s16x8*)&sA[arow + m*1024 + ck];
    bf0 = *(const s16x8*)&sB[brow + ck];            // n-tile 0 (gate cols s=0)
    bf1 = *(const s16x8*)&sB[brow + 2*1024 + ck];   // n-tile 2 (gate cols s=1)
    #pragma unroll
    for (int m = 0; m < 4; m++) {
      accr[m][0] = MFMA_BF16(af[m], bf0, accr[m][0]);
      accr[m][1] = MFMA_BF16(af[m], bf1, accr[m][1]);
    }
  }

  // epilogue: acc[m][2s]=gate_pre, acc[m][2s+1]=out_pre, accr[m][s]=retrieved
  #pragma unroll
  for (int s = 0; s < 2; s++) {
    int ocol = colblk*128 + wn*32 + s*16 + ln15;
    float gbv = gate_b[ocol], obv = out_b[ocol];
    #pragma unroll
    for (int m = 0; m < 4; m++) {
      #pragma unroll
      for (int i = 0; i < 4; i++) {
        size_t r = r0 + wm*64 + m*16 + hi*4 + i;
        float gg = acc[m][s*2+0][i] + gbv;
        float go = acc[m][s*2+1][i] + obv;
        float h  = 0.5f*go*(1.0f + erff(go*0.70710678118654752f));  // exact gelu
        float sg = 1.0f/(1.0f + __expf(-gg));
        float rv = accr[m][s][i];
        float xv = bf2f(A[r*1088 + ocol]);
        y[r*1024 + ocol] = h + sg*rv + (1.0f - sg)*xv;
      }
    }
  }
}

// ---------------- K3: LayerNorm in place (wave per row) ---------------------
__global__ __launch_bounds__(256) void k_ln(float* __restrict__ y, const float* __restrict__ g,
                                            const float* __restrict__ b) {
  int row  = blockIdx.x*4 + (threadIdx.x >> 6);
  int lane = threadIdx.x & 63;
  float4* p = (float4*)(y + (size_t)row*1024);
  float4 v[4];
  #pragma unroll
  for (int i = 0; i < 4; i++) v[i] = p[lane + 64*i];
  float s = 0.f;
  #pragma unroll
  for (int i = 0; i < 4; i++) s += v[i].x + v[i].y + v[i].z + v[i].w;
  #pragma unroll
  for (int o = 32; o; o >>= 1) s += __shfl_xor(s, o);
  float mu = s * (1.0f/1024.0f);
  float vs = 0.f;
  #pragma unroll
  for (int i = 0; i < 4; i++) {
    float d0 = v[i].x-mu, d1 = v[i].y-mu, d2 = v[i].z-mu, d3 = v[i].w-mu;
    vs += d0*d0 + d1*d1 + d2*d2 + d3*d3;
  }
  #pragma unroll
  for (int o = 32; o; o >>= 1) vs += __shfl_xor(vs, o);
  float inv = 1.0f / sqrtf(vs*(1.0f/1024.0f) + 1e-5f);
  const float4* gp = (const float4*)g;
  const float4* bp = (const float4*)b;
  #pragma unroll
  for (int i = 0; i < 4; i++) {
    float4 gv = gp[lane+64*i], bv = bp[lane+64*i], o4;
    o4.x = (v[i].x-mu)*inv*gv.x + bv.x;
    o4.y = (v[i].y-mu)*inv*gv.y + bv.y;
    o4.z = (v[i].z-mu)*inv*gv.z + bv.z;
    o4.w = (v[i].w-mu)*inv*gv.w + bv.w;
    p[lane + 64*i] = o4;
  }
}

// ---------------- launch ----------------------------------------------------
extern "C" void kernel_launch(void* const* d_in, const int* in_sizes, int n_in,
                              void* d_out, int out_size, void* d_ws, size_t ws_size,
                              hipStream_t stream) {
  const float* x         = (const float*)d_in[0];
  const float* key_w     = (const float*)d_in[1];
  const float* out_w     = (const float*)d_in[2];
  const float* out_b     = (const float*)d_in[3];
  const float* gate_w    = (const float*)d_in[4];
  const float* gate_b    = (const float*)d_in[5];
  const float* ln_g      = (const float*)d_in[6];
  const float* ln_b      = (const float*)d_in[7];
  const float* pos_table = (const float*)d_in[8];
  const float* mem_keys  = (const float*)d_in[9];
  const float* mem_vals  = (const float*)d_in[10];
  const float* mem_age   = (const float*)d_in[11];
  const float* mem_conf  = (const float*)d_in[12];
  const int*   slot_order= (const int*)d_in[13];

  char* ws = (char*)d_ws;
  u16*   A    = (u16*)(ws + 0);            // A_ext bf16 [16384][1088]  35.7 MB
  u16*   Wcat = (u16*)(ws + 36700160);     // Wcat_ext bf16 [2048][1088] 4.5 MB
  u16*   Vcat = (u16*)(ws + 41943040);     // Vcat bf16 [2048][64]     256 KB
  u16*   Wk   = (u16*)(ws + 42205184);     // key_w bf16 [32][1024]     64 KB
  float* kwp  = (float*)(ws + 42270720);   // keys_with_pos [64][33]   8448 B
  float* biasv= (float*)(ws + 42279168);   // salience bias [64]
  float* y    = (float*)d_out;

  hipLaunchKernelGGL(k_prep,  dim3(97),   dim3(256),  0, stream,
                     mem_keys, pos_table, slot_order, mem_age, mem_conf,
                     key_w, mem_vals, gate_w, out_w, kwp, biasv, Wk, Vcat, Wcat);
  hipLaunchKernelGGL(k_front, dim3(288),  dim3(256),  0, stream,
                     x, gate_w, out_w, Wk, kwp, biasv, A, Wcat);
  hipLaunchKernelGGL(k_gemm,  dim3(512),  dim3(1024), 0, stream,
                     A, Wcat, Vcat, out_b, gate_b, y);
  hipLaunchKernelGGL(k_ln,    dim3(4096), dim3(256),  0, stream, y, ln_g, ln_b);
}

// Round 13
// 174.725 us; speedup vs baseline: 1.6736x; 1.0760x over previous
//
#include <hip/hip_runtime.h>
#include <hip/hip_bf16.h>
#include <math.h>

// EpisodicMemory fused pipeline for MI355X (gfx950).
// B=16384, HID=1024, SLOTS=64, KD=32.
// Round 13: 3 kernels. k_front absorbs all prep (slot salience computed
// per-block; key_w staged f32->bf16 in-kernel; PV mini-GEMM + Vcat in extra
// blocks). k_gemm: algebraic form (K=1088 + retrieved tile), 256x256 tile,
// 1024 threads, 64KB LDS, both-sides swizzle; writes y in BF16 (halves LN
// traffic). k_ln: bf16 in -> f32 out.

typedef float    f32x4 __attribute__((ext_vector_type(4)));
typedef short    s16x8 __attribute__((ext_vector_type(8)));
typedef unsigned short u16;
typedef unsigned short u16x8 __attribute__((ext_vector_type(8)));

#define MFMA_BF16(a,b,c) __builtin_amdgcn_mfma_f32_16x16x32_bf16((a),(b),(c),0,0,0)

__device__ __forceinline__ void async16(void* lds, const void* g) {
  __builtin_amdgcn_global_load_lds((const __attribute__((address_space(1))) void*)g,
                                   (__attribute__((address_space(3))) void*)lds, 16, 0, 0);
}

__device__ __forceinline__ u16 f2bf(float f) {
  unsigned u = __float_as_uint(f);
  u += 0x7fffu + ((u >> 16) & 1u);   // RNE
  return (u16)(u >> 16);
}
__device__ __forceinline__ float bf2f(u16 h) {
  return __uint_as_float(((unsigned)h) << 16);
}
__device__ __forceinline__ int ocol_of(int p) { return ((p >> 5) << 4) + (p & 15); }

// ---------------- K1: fused front ------------------------------------------
// blocks 0..255:   x->bf16 into A_ext + qk MFMA + softmax -> attn cols
// blocks 256..287: gate/out LEFT halves -> Wcat_ext[.][0..1023] (interleaved)
// blocks 288..319: Vcat transpose + PV mini-GEMM -> Wcat_ext[.][1024..1087]
__global__ __launch_bounds__(256) void k_front(
    const float* __restrict__ x, const float* __restrict__ gate_w,
    const float* __restrict__ out_w, const float* __restrict__ key_w,
    const float* __restrict__ mem_vals, const float* __restrict__ mem_keys,
    const float* __restrict__ pos_table, const int* __restrict__ slot_order,
    const float* __restrict__ mem_age, const float* __restrict__ mem_conf,
    u16* __restrict__ A, u16* __restrict__ Wcat, u16* __restrict__ Vcat) {
  const int b = blockIdx.x, tid = threadIdx.x;

  if (b >= 288) {            // ---- Vcat + PV mini-GEMM (64 p-rows each) ----
    const int pb = (b - 288) * 64;
    for (int e = tid; e < 64*64; e += 256) {
      int pl = e >> 6, s = e & 63;
      int p = pb + pl;
      Vcat[(size_t)p*64 + s] = f2bf(mem_vals[(size_t)s*1024 + ocol_of(p)]);
    }
    __shared__ __align__(16) u16 sW[64*80];
    __shared__ __align__(16) u16 sV[64*80];
    const int lane = tid & 63, w = tid >> 6;
    const int ln15 = lane & 15, hi = lane >> 4;
    f32x4 acc[4];
    #pragma unroll
    for (int n = 0; n < 4; n++) acc[n] = {0.f,0.f,0.f,0.f};
    for (int kt = 0; kt < 16; ++kt) {
      #pragma unroll
      for (int j = 0; j < 4; j++) {
        int idx = tid + j*256;
        int row = idx >> 4, g4 = idx & 15;
        int p = pb + row;
        const float* wsrc = ((p >> 4) & 1) ? out_w : gate_w;
        float4 v = *(const float4*)&wsrc[(size_t)ocol_of(p)*2048 + 1024 + kt*64 + g4*4];
        ushort4 o; o.x=f2bf(v.x); o.y=f2bf(v.y); o.z=f2bf(v.z); o.w=f2bf(v.w);
        *(ushort4*)&sW[row*80 + g4*4] = o;
        float4 u = *(const float4*)&mem_vals[(size_t)row*1024 + kt*64 + g4*4];
        ushort4 p2; p2.x=f2bf(u.x); p2.y=f2bf(u.y); p2.z=f2bf(u.z); p2.w=f2bf(u.w);
        *(ushort4*)&sV[row*80 + g4*4] = p2;
      }
      __syncthreads();
      #pragma unroll
      for (int kk = 0; kk < 2; kk++) {
        int kb = kk*32 + hi*8;
        s16x8 a = *(const s16x8*)&sW[(w*16 + ln15)*80 + kb];
        #pragma unroll
        for (int n = 0; n < 4; n++) {
          s16x8 bv = *(const s16x8*)&sV[(n*16 + ln15)*80 + kb];
          acc[n] = MFMA_BF16(a, bv, acc[n]);
        }
      }
      __syncthreads();
    }
    #pragma unroll
    for (int n = 0; n < 4; n++)
      #pragma unroll
      for (int i = 0; i < 4; i++) {
        int p = pb + w*16 + hi*4 + i;
        Wcat[(size_t)p*1088 + 1024 + n*16 + ln15] = f2bf(acc[n][i]);
      }
    return;
  }

  if (b >= 256) {            // ---- left halves -> Wcat_ext ----
    for (int g = (b-256)*256 + tid; g < 524288; g += 32*256) {
      float4 v; int t, pb2;
      if (g < 262144) { t = g;          v = *(const float4*)&gate_w[(size_t)(t>>8)*2048 + (t&255)*4]; pb2 = 0; }
      else            { t = g - 262144; v = *(const float4*)&out_w [(size_t)(t>>8)*2048 + (t&255)*4]; pb2 = 16; }
      int row = t >> 8, grp = t & 255;
      int p = ((row>>4)<<5) + pb2 + (row&15);
      ushort4 o; o.x=f2bf(v.x); o.y=f2bf(v.y); o.z=f2bf(v.z); o.w=f2bf(v.w);
      *(ushort4*)(Wcat + ((size_t)p*1088 + grp*4)) = o;
    }
    return;
  }

  // ---- main: x->bf16, qk, softmax, attn ----
  __shared__ __align__(16) u16 sX[64*72];    // x tile bf16, padded stride 72
  __shared__ __align__(16) u16 sWk[32*72];   // key_w slice bf16
  __shared__ float sQK[64*33];
  __shared__ float sK[64*33];
  __shared__ float sBias[64];
  __shared__ float sQn[64*32];

  const int lane = tid & 63, w = tid >> 6;
  const int ln15 = lane & 15, hi = lane >> 4;
  const size_t r0 = (size_t)b * 64;

  if (tid < 64) {            // in-block slot prep (key_w etc. L3-resident)
    int s = tid;
    float age  = mem_age[s];
    float freq = fmaxf(age, 1.0f);
    float fm = freq;
    #pragma unroll
    for (int o = 32; o; o >>= 1) fm = fmaxf(fm, __shfl_xor(fm, o));
    float freq_norm = logf(freq + 1.0f) / (logf(fm + 2.0f) + 1e-8f);
    float recency = expf(-age * (1.0f/200.0f));
    sBias[s] = 0.2f*recency + 0.15f*freq_norm + 0.1f*mem_conf[s] + 0.08f;

    int idx = slot_order[s] & 63;
    float k[32]; float ss = 0.f;
    #pragma unroll
    for (int d = 0; d < 32; d++) {
      float v = mem_keys[s*32+d] + 0.1f*pos_table[idx*32+d];
      k[d] = v; ss += v*v;
    }
    float inv = 1.0f / fmaxf(sqrtf(ss), 1e-12f);
    #pragma unroll
    for (int d = 0; d < 32; d++) sK[s*33+d] = k[d]*inv;
  }

  // ---- qk = x @ key_w^T via MFMA, fused with x->bf16 conversion ----
  f32x4 acc0 = {0.f,0.f,0.f,0.f}, acc1 = {0.f,0.f,0.f,0.f};
  const int xrow = tid >> 4, xc4 = tid & 15;
  for (int k0 = 0; k0 < 1024; k0 += 64) {
    #pragma unroll
    for (int j = 0; j < 4; j++) {
      int row = xrow + j*16;
      float4 v = *(const float4*)&x[(r0+row)*1024 + k0 + xc4*4];
      ushort4 o; o.x=f2bf(v.x); o.y=f2bf(v.y); o.z=f2bf(v.z); o.w=f2bf(v.w);
      *(ushort4*)&sX[row*72 + xc4*4] = o;
      *(ushort4*)&A[(r0+row)*1088 + k0 + xc4*4] = o;    // A_ext left (x bf16)
    }
    #pragma unroll
    for (int j = 0; j < 2; j++) {                        // key_w slice -> bf16
      int idx = tid + j*256;
      int row = idx >> 4, c4 = idx & 15;
      float4 v = *(const float4*)&key_w[(size_t)row*1024 + k0 + c4*4];
      ushort4 o; o.x=f2bf(v.x); o.y=f2bf(v.y); o.z=f2bf(v.z); o.w=f2bf(v.w);
      *(ushort4*)&sWk[row*72 + c4*4] = o;
    }
    __syncthreads();
    #pragma unroll
    for (int kk = 0; kk < 2; kk++) {
      int kb = kk*32 + hi*8;
      s16x8 a  = *(const s16x8*)&sX[(w*16 + ln15)*72 + kb];
      s16x8 b0 = *(const s16x8*)&sWk[ln15*72 + kb];
      s16x8 b1 = *(const s16x8*)&sWk[(16+ln15)*72 + kb];
      acc0 = MFMA_BF16(a, b0, acc0);
      acc1 = MFMA_BF16(a, b1, acc1);
    }
    __syncthreads();
  }
  #pragma unroll
  for (int i = 0; i < 4; i++) {
    sQK[(w*16 + hi*4 + i)*33 + ln15]      = acc0[i];
    sQK[(w*16 + hi*4 + i)*33 + 16 + ln15] = acc1[i];
  }
  __syncthreads();

  // ---- softmax over 64 slots; write attn bf16 to A_ext[1024..1087] ----
  int d = lane & 31;
  for (int j = 0; j < 16; j++) {
    int rl = w*16 + j;
    float v = sQK[rl*33 + d];
    float sq = v*v;
    #pragma unroll
    for (int o = 16; o; o >>= 1) sq += __shfl_xor(sq, o);   // 32-group sum
    float qn = v / fmaxf(sqrtf(sq), 1e-12f);
    if (lane < 32) sQn[rl*32 + d] = qn;
    float accs = 0.f;
    #pragma unroll
    for (int dd = 0; dd < 32; dd++) accs += sK[lane*33+dd] * sQn[rl*32+dd];
    float sim = accs * 0.17677669529663687f;   // 1/sqrt(32)
    float sal = fminf(fmaxf(0.45f*sim + sBias[lane], 0.0f), 1.0f);
    float mx = sal;
    #pragma unroll
    for (int o = 32; o; o >>= 1) mx = fmaxf(mx, __shfl_xor(mx, o));
    float e = expf(sal - mx);
    float sm = e;
    #pragma unroll
    for (int o = 32; o; o >>= 1) sm += __shfl_xor(sm, o);
    A[(r0 + rl)*1088 + 1024 + lane] = f2bf(e / sm);
  }
}

// ---------------- K2: GEMM (K=1088 + retrieved tile) + fused epilogue -------
// C = A_ext[16384,1088] @ Wcat_ext[2048,1088]^T  (gate/out interleaved),
// then one extra K-tile: acc_r = attn-tile @ Vcat-slice = retrieved values.
// 256x256 tile, 16 waves (4x4, wave 64x64), BK=64, single 64KB LDS buffer.
// Writes y in BF16 (pre-LN) to halve LayerNorm traffic.
__global__ __launch_bounds__(1024, 2) void k_gemm(
    const u16* __restrict__ A, const u16* __restrict__ Wcat,
    const u16* __restrict__ Vcat, const float* __restrict__ out_b,
    const float* __restrict__ gate_b, u16* __restrict__ yb) {
  __shared__ __align__(16) u16 sA[16384];   // 256 rows x 64 (swizzled)
  __shared__ __align__(16) u16 sB[16384];   // 256 rows x 64 (swizzled)

  const int tid = threadIdx.x, lane = tid & 63, w = tid >> 6;
  const int ln15 = lane & 15, hi = lane >> 4, p7 = ln15 & 7;
  const int wm = w >> 2, wn = w & 3;        // 4x4 waves, wave = 64x64

  const int colblk = blockIdx.x & 7;        // XCD-resident weight panel
  const int rowblk = blockIdx.x >> 3;       // 0..63
  const size_t r0 = (size_t)rowblk * 256;
  const size_t c0 = (size_t)colblk * 256;

  const u16* gA = A    + r0 * 1088;
  const u16* gB = Wcat + c0 * 1088;
  const u16* gV = Vcat + c0 * 64;

  // staging: 2048 chunks of 16B per side, 2/thread each; physical chunk pc
  // of row r holds logical chunk pc ^ (r&7) (inverse swizzle on global src).
  int offA[2], offB[2], offV[2];
  #pragma unroll
  for (int j = 0; j < 2; j++) {
    int c = tid + j*1024, row = c >> 3, pc = c & 7;
    int sw = ((pc ^ (row & 7)) << 3);
    offA[j] = row*1088 + sw;
    offB[j] = row*1088 + sw;
    offV[j] = row*64   + sw;
  }

  const int ck0 = (hi ^ p7) * 8;            // kk=0: logical chunk hi
  const int ck1 = ((4 | hi) ^ p7) * 8;      // kk=1: logical chunk 4|hi
  const int arow = (wm*64 + ln15) * 64;     // + m*1024
  const int brow = (wn*64 + ln15) * 64;     // + n*1024

  f32x4 acc[4][4], accr[4][2];
  #pragma unroll
  for (int m = 0; m < 4; m++) {
    #pragma unroll
    for (int n = 0; n < 4; n++) acc[m][n] = {0.f, 0.f, 0.f, 0.f};
    accr[m][0] = {0.f,0.f,0.f,0.f}; accr[m][1] = {0.f,0.f,0.f,0.f};
  }

  #pragma unroll 1
  for (int kt = 0; kt < 17; ++kt) {
    const int ko = kt * 64;
    #pragma unroll
    for (int j = 0; j < 2; j++) {
      async16(&sA[(tid + j*1024)*8], gA + offA[j] + ko);
      async16(&sB[(tid + j*1024)*8], gB + offB[j] + ko);
    }
    __syncthreads();   // drains vmcnt(0): staged tile visible to all waves
    #pragma unroll
    for (int kk = 0; kk < 2; kk++) {
      const int ck = kk ? ck1 : ck0;
      s16x8 af[4], bfr[4];
      #pragma unroll
      for (int m = 0; m < 4; m++) af[m]  = *(const s16x8*)&sA[arow + m*1024 + ck];
      #pragma unroll
      for (int n = 0; n < 4; n++) bfr[n] = *(const s16x8*)&sB[brow + n*1024 + ck];
      #pragma unroll
      for (int m = 0; m < 4; m++)
        #pragma unroll
        for (int n = 0; n < 4; n++)
          acc[m][n] = MFMA_BF16(af[m], bfr[n], acc[m][n]);
    }
    __syncthreads();   // tile fully consumed before next stage overwrites
  }

  // retrieved pass: sA still holds kt=16 (attn tile); stage Vcat slice -> sB
  #pragma unroll
  for (int j = 0; j < 2; j++) async16(&sB[(tid + j*1024)*8], gV + offV[j]);
  __syncthreads();
  #pragma unroll
  for (int kk = 0; kk < 2; kk++) {
    const int ck = kk ? ck1 : ck0;
    s16x8 af[4], bf0, bf1;
    #pragma unroll
    for (int m = 0; m < 4; m++) af[m] = *(const s16x8*)&sA[arow + m*1024 + ck];
    bf0 = *(const s16x8*)&sB[brow + ck];            // n-tile 0 (gate cols s=0)
    bf1 = *(const s16x8*)&sB[brow + 2*1024 + ck];   // n-tile 2 (gate cols s=1)
    #pragma unroll
    for (int m = 0; m < 4; m++) {
      accr[m][0] = MFMA_BF16(af[m], bf0, accr[m][0]);
      accr[m][1] = MFMA_BF16(af[m], bf1, accr[m][1]);
    }
  }

  // epilogue: acc[m][2s]=gate_pre, acc[m][2s+1]=out_pre, accr[m][s]=retrieved
  #pragma unroll
  for (int s = 0; s < 2; s++) {
    int ocol = colblk*128 + wn*32 + s*16 + ln15;
    float gbv = gate_b[ocol], obv = out_b[ocol];
    #pragma unroll
    for (int m = 0; m < 4; m++) {
      #pragma unroll
      for (int i = 0; i < 4; i++) {
        size_t r = r0 + wm*64 + m*16 + hi*4 + i;
        float gg = acc[m][s*2+0][i] + gbv;
        float go = acc[m][s*2+1][i] + obv;
        float h  = 0.5f*go*(1.0f + erff(go*0.70710678118654752f));  // exact gelu
        float sg = 1.0f/(1.0f + __expf(-gg));
        float rv = accr[m][s][i];
        float xv = bf2f(A[r*1088 + ocol]);
        yb[r*1024 + ocol] = f2bf(h + sg*rv + (1.0f - sg)*xv);
      }
    }
  }
}

// ---------------- K3: LayerNorm (bf16 in -> f32 out, wave per row) ----------
__global__ __launch_bounds__(256) void k_ln(const u16* __restrict__ yb,
                                            const float* __restrict__ g,
                                            const float* __restrict__ b,
                                            float* __restrict__ out) {
  int row  = blockIdx.x*4 + (threadIdx.x >> 6);
  int lane = threadIdx.x & 63;
  const u16* p = yb + (size_t)row*1024 + lane*16;
  u16x8 h0 = *(const u16x8*)p;
  u16x8 h1 = *(const u16x8*)(p + 8);
  float v[16];
  #pragma unroll
  for (int i = 0; i < 8; i++) { v[i] = bf2f((u16)h0[i]); v[8+i] = bf2f((u16)h1[i]); }
  float s = 0.f;
  #pragma unroll
  for (int i = 0; i < 16; i++) s += v[i];
  #pragma unroll
  for (int o = 32; o; o >>= 1) s += __shfl_xor(s, o);
  float mu = s * (1.0f/1024.0f);
  float vs = 0.f;
  #pragma unroll
  for (int i = 0; i < 16; i++) { float d0 = v[i]-mu; vs += d0*d0; }
  #pragma unroll
  for (int o = 32; o; o >>= 1) vs += __shfl_xor(vs, o);
  float inv = 1.0f / sqrtf(vs*(1.0f/1024.0f) + 1e-5f);
  const float4* gp = (const float4*)(g + lane*16);
  const float4* bp = (const float4*)(b + lane*16);
  float4* op = (float4*)(out + (size_t)row*1024 + lane*16);
  #pragma unroll
  for (int i = 0; i < 4; i++) {
    float4 gv = gp[i], bv = bp[i], o4;
    o4.x = (v[i*4+0]-mu)*inv*gv.x + bv.x;
    o4.y = (v[i*4+1]-mu)*inv*gv.y + bv.y;
    o4.z = (v[i*4+2]-mu)*inv*gv.z + bv.z;
    o4.w = (v[i*4+3]-mu)*inv*gv.w + bv.w;
    op[i] = o4;
  }
}

// ---------------- launch ----------------------------------------------------
extern "C" void kernel_launch(void* const* d_in, const int* in_sizes, int n_in,
                              void* d_out, int out_size, void* d_ws, size_t ws_size,
                              hipStream_t stream) {
  const float* x         = (const float*)d_in[0];
  const float* key_w     = (const float*)d_in[1];
  const float* out_w     = (const float*)d_in[2];
  const float* out_b     = (const float*)d_in[3];
  const float* gate_w    = (const float*)d_in[4];
  const float* gate_b    = (const float*)d_in[5];
  const float* ln_g      = (const float*)d_in[6];
  const float* ln_b      = (const float*)d_in[7];
  const float* pos_table = (const float*)d_in[8];
  const float* mem_keys  = (const float*)d_in[9];
  const float* mem_vals  = (const float*)d_in[10];
  const float* mem_age   = (const float*)d_in[11];
  const float* mem_conf  = (const float*)d_in[12];
  const int*   slot_order= (const int*)d_in[13];

  char* ws = (char*)d_ws;
  u16*   A    = (u16*)(ws + 0);            // A_ext bf16 [16384][1088]  35.7 MB
  u16*   Wcat = (u16*)(ws + 36700160);     // Wcat_ext bf16 [2048][1088] 4.5 MB
  u16*   Vcat = (u16*)(ws + 41943040);     // Vcat bf16 [2048][64]     256 KB
  u16*   yb   = (u16*)(ws + 42205184);     // y bf16 [16384][1024]      32 MB
  float* y    = (float*)d_out;

  hipLaunchKernelGGL(k_front, dim3(320),  dim3(256),  0, stream,
                     x, gate_w, out_w, key_w, mem_vals, mem_keys, pos_table,
                     slot_order, mem_age, mem_conf, A, Wcat, Vcat);
  hipLaunchKernelGGL(k_gemm,  dim3(512),  dim3(1024), 0, stream,
                     A, Wcat, Vcat, out_b, gate_b, yb);
  hipLaunchKernelGGL(k_ln,    dim3(4096), dim3(256),  0, stream,
                     yb, ln_g, ln_b, y);
}